// Round 1
// baseline (967.380 us; speedup 1.0000x reference)
//
#include <hip/hip_runtime.h>

#define KORD   10
#define MAXDEG 64
#define NB     2048        // nodes per graph
#define NBATCH 8
#define NROWS  16384       // NBATCH * NB
#define HD     256         // hidden per conv
#define HFULL  768

// ---------------------------------------------------------------------------
// q[m] = [z^m] sum_k relu(coe[k]) * C(K,k)/2^K * (1-z)^k (1+z)^{K-k}
// (monomial coefficients of the Bernstein filter in powers of Ahat).
// zstate[m] = 1 iff q[j]==0 for all j>=m  (=> Horner state acc_m is all-zero).
// Exact in fp64 for dyadic coe (e.g. coe=1 -> q = [1,0,...,0] exactly).
// ---------------------------------------------------------------------------
__global__ void compute_q_kernel(const float* __restrict__ coe,
                                 float* __restrict__ qf,
                                 int* __restrict__ zstate) {
  if (threadIdx.x != 0 || blockIdx.x != 0) return;
  double C[KORD + 1][KORD + 1];
  for (int i = 0; i <= KORD; ++i)
    for (int j = 0; j <= KORD; ++j) C[i][j] = 0.0;
  for (int i = 0; i <= KORD; ++i) {
    C[i][0] = 1.0;
    for (int j = 1; j <= i; ++j) C[i][j] = C[i - 1][j - 1] + C[i - 1][j];
  }
  double q[KORD + 1];
  for (int m = 0; m <= KORD; ++m) q[m] = 0.0;
  for (int k = 0; k <= KORD; ++k) {
    double t = (double)coe[k];
    if (t < 0.0) t = 0.0;                      // relu(coe)
    double ck = t * C[KORD][k] / 1024.0;       // * C(K,k)/2^K
    for (int m = 0; m <= KORD; ++m) {
      double s = 0.0;
      for (int j = 0; j <= k && j <= m; ++j) {
        int rem = m - j;
        if (rem <= KORD - k) {
          double term = C[k][j] * C[KORD - k][rem];
          s += (j & 1) ? -term : term;
        }
      }
      q[m] += ck * s;
    }
  }
  for (int m = 0; m <= KORD; ++m) qf[m] = (float)q[m];
  zstate[KORD + 1] = 1;
  int z = 1;
  for (int m = KORD; m >= 0; --m) {
    if (q[m] != 0.0) z = 0;
    zstate[m] = z;
  }
}

// ---------------------------------------------------------------------------
// Build fixed-stride adjacency lists + degree + D^-1/2.
// One 64-lane wave per row; ballot/popcount compaction.
// ---------------------------------------------------------------------------
__global__ __launch_bounds__(256) void build_adj_kernel(
    const float* __restrict__ adj,
    int* __restrict__ cnt, float* __restrict__ dis,
    int* __restrict__ colidx) {
  const int wave = threadIdx.x >> 6;
  const int lane = threadIdx.x & 63;
  const int row  = blockIdx.x * 4 + wave;          // [0, NROWS)
  const int b    = row >> 11;                      // row / 2048
  const float* arow = adj + (size_t)row * NB;
  int* ci = colidx + (size_t)row * MAXDEG;
  int base = 0;
  for (int c0 = 0; c0 < NB; c0 += 64) {
    float v = arow[c0 + lane];
    unsigned long long mask = __ballot(v > 0.0f);
    if (v > 0.0f) {
      int pos = base + __popcll(mask & ((1ull << lane) - 1ull));
      if (pos < MAXDEG) ci[pos] = (b << 11) + c0 + lane;
    }
    base += __popcll(mask);
  }
  if (lane == 0) {
    cnt[row] = base > MAXDEG ? MAXDEG : base;
    dis[row] = base > 0 ? rsqrtf((float)base) : 0.0f;
  }
}

// ---------------------------------------------------------------------------
// fp32 tiled GEMM: out[M,N] = A[M,Kd] @ W[Kd,N] + bias
// A is virtual: sumMode=1 -> A = A0 + A1 (both width Kd);
//               else      -> cols [0,splitK) from A0, rest from A1.
// BM=BN=64, BK=16, 256 threads, 4x4 micro-tile.
// ---------------------------------------------------------------------------
__global__ __launch_bounds__(256) void gemm_kernel(
    int Kd,
    const float* __restrict__ A0, int lda0,
    const float* __restrict__ A1, int lda1,
    int splitK, int sumMode,
    const float* __restrict__ W, int N,
    const float* __restrict__ bias,
    float* __restrict__ out, int ldo) {
  __shared__ float As[16][68];
  __shared__ float Ws[16][68];
  const int t  = threadIdx.x;
  const int kk = t & 15;          // A-load: k within tile
  const int rg = t >> 4;          // A-load: row group 0..15
  const int wn = t & 63;          // W-load: col
  const int wk = t >> 6;          // W-load: k group 0..3
  const int tm = t >> 4;          // compute: row group 0..15
  const int tn = t & 15;          // compute: col group 0..15
  const int row0 = blockIdx.y * 64;
  const int col0 = blockIdx.x * 64;

  float acc[4][4];
#pragma unroll
  for (int i = 0; i < 4; ++i)
#pragma unroll
    for (int j = 0; j < 4; ++j) acc[i][j] = 0.0f;

  const int nkt = Kd >> 4;
  for (int kt = 0; kt < nkt; ++kt) {
    const int k = (kt << 4) + kk;
#pragma unroll
    for (int i = 0; i < 4; ++i) {
      const int r = row0 + rg + 16 * i;
      float v;
      if (sumMode)
        v = A0[(size_t)r * lda0 + k] + A1[(size_t)r * lda1 + k];
      else if (k < splitK)
        v = A0[(size_t)r * lda0 + k];
      else
        v = A1[(size_t)r * lda1 + (k - splitK)];
      As[kk][rg + 16 * i] = v;
    }
#pragma unroll
    for (int i = 0; i < 4; ++i) {
      const int kw = wk + 4 * i;
      Ws[kw][wn] = W[(size_t)((kt << 4) + kw) * N + (col0 + wn)];
    }
    __syncthreads();
#pragma unroll
    for (int k2 = 0; k2 < 16; ++k2) {
      const float4 av = *(const float4*)&As[k2][tm * 4];
      const float4 wv = *(const float4*)&Ws[k2][tn * 4];
      acc[0][0] += av.x * wv.x; acc[0][1] += av.x * wv.y;
      acc[0][2] += av.x * wv.z; acc[0][3] += av.x * wv.w;
      acc[1][0] += av.y * wv.x; acc[1][1] += av.y * wv.y;
      acc[1][2] += av.y * wv.z; acc[1][3] += av.y * wv.w;
      acc[2][0] += av.z * wv.x; acc[2][1] += av.z * wv.y;
      acc[2][2] += av.z * wv.z; acc[2][3] += av.z * wv.w;
      acc[3][0] += av.w * wv.x; acc[3][1] += av.w * wv.y;
      acc[3][2] += av.w * wv.z; acc[3][3] += av.w * wv.w;
    }
    __syncthreads();
  }
  const float4 bv = *(const float4*)&bias[col0 + tn * 4];
#pragma unroll
  for (int i = 0; i < 4; ++i) {
    const int r = row0 + tm * 4 + i;
    float4 o;
    o.x = acc[i][0] + bv.x;
    o.y = acc[i][1] + bv.y;
    o.z = acc[i][2] + bv.z;
    o.w = acc[i][3] + bv.w;
    *(float4*)&out[(size_t)r * ldo + col0 + tn * 4] = o;
  }
}

// ---------------------------------------------------------------------------
// Horner step m: out = Ahat @ accin + q[m] * h      (256 channels)
// zstate[m]   == 1 -> out is all-zero & never read: early-exit (unless final)
// zstate[m+1] == 1 -> accin is all-zero: skip gather
// Wave per row, lane handles 4 channels (float4).
// ---------------------------------------------------------------------------
__global__ __launch_bounds__(256) void spmm_step_kernel(
    const float* __restrict__ accin,
    const float* __restrict__ h,
    const int* __restrict__ cnt,
    const float* __restrict__ dis,
    const int* __restrict__ colidx,
    const float* __restrict__ qf,
    const int* __restrict__ zstate,
    int m, float* __restrict__ outp, int ldo, int do_relu, int is_final) {
  if (!is_final && zstate[m]) return;
  const int wave = threadIdx.x >> 6;
  const int lane = threadIdx.x & 63;
  const int row  = blockIdx.x * 4 + wave;
  const float qm = qf[m];
  const int c0 = lane * 4;
  float4 s = make_float4(0.f, 0.f, 0.f, 0.f);
  if (!zstate[m + 1]) {
    const int deg = cnt[row];
    const float di = dis[row];
    const int* ci = colidx + (size_t)row * MAXDEG;
    for (int e = 0; e < deg; ++e) {
      const int nbr = ci[e];
      const float w = di * dis[nbr];
      const float4 v = *(const float4*)&accin[((size_t)nbr << 8) + c0];
      s.x += w * v.x; s.y += w * v.y; s.z += w * v.z; s.w += w * v.w;
    }
  }
  const float4 hv = *(const float4*)&h[((size_t)row << 8) + c0];
  s.x += qm * hv.x; s.y += qm * hv.y; s.z += qm * hv.z; s.w += qm * hv.w;
  if (do_relu) {
    s.x = fmaxf(s.x, 0.f); s.y = fmaxf(s.y, 0.f);
    s.z = fmaxf(s.z, 0.f); s.w = fmaxf(s.w, 0.f);
  }
  *(float4*)&outp[(size_t)row * ldo + c0] = s;
}

// ---------------------------------------------------------------------------
extern "C" void kernel_launch(void* const* d_in, const int* in_sizes, int n_in,
                              void* d_out, int out_size, void* d_ws, size_t ws_size,
                              hipStream_t stream) {
  const float* adj  = (const float*)d_in[0];
  const float* x    = (const float*)d_in[1];
  const float* coe  = (const float*)d_in[2];
  const float* W0   = (const float*)d_in[3];
  const float* b0   = (const float*)d_in[4];
  const float* W1   = (const float*)d_in[5];
  const float* b1   = (const float*)d_in[6];
  const float* W2   = (const float*)d_in[7];
  const float* b2   = (const float*)d_in[8];
  const float* Wout = (const float*)d_in[9];
  const float* bout = (const float*)d_in[10];
  float* outp = (float*)d_out;

  // Scratch inside d_out (dead until final GEMM): two acc ping-pong buffers
  // + the pre-poly h buffer. 3 * 16 MB = 48 MB = exactly d_out.
  float* accbuf[2];
  accbuf[0] = outp;
  accbuf[1] = outp + (size_t)NROWS * HD;
  float* bufH = outp + (size_t)2 * NROWS * HD;

  char* ws = (char*)d_ws;
  float* qf     = (float*)(ws + 0);
  int*   zstate = (int*)(ws + 256);
  int*   cnt    = (int*)(ws + 512);
  float* dis    = (float*)(ws + 512 + 4 * NROWS);
  int*   colidx = (int*)(ws + 512 + 8 * NROWS);
  float* bern   = (float*)(ws + 512 + 8 * NROWS + 4 * (size_t)NROWS * MAXDEG);
  // total ws use: 512 + 128K + 4MB + 48MB ~= 52.3 MB

  hipLaunchKernelGGL(compute_q_kernel, dim3(1), dim3(64), 0, stream,
                     coe, qf, zstate);
  hipLaunchKernelGGL(build_adj_kernel, dim3(NROWS / 4), dim3(256), 0, stream,
                     adj, cnt, dis, colidx);

  // One BernConv layer: GEMM -> Horner(K SpMM steps) -> ReLU into bern slice
  auto run_layer = [&](int Kd, int splitK, const float* W, const float* bias,
                       int layer) {
    hipLaunchKernelGGL(gemm_kernel, dim3(HD / 64, NROWS / 64), dim3(256), 0,
                       stream, Kd, x, HFULL, bern, HFULL, splitK, 0, W, HD,
                       bias, bufH, HD);
    for (int m = KORD; m >= 1; --m) {
      hipLaunchKernelGGL(spmm_step_kernel, dim3(NROWS / 4), dim3(256), 0,
                         stream, accbuf[(m + 1) & 1], bufH, cnt, dis, colidx,
                         qf, zstate, m, accbuf[m & 1], HD, 0, 0);
    }
    hipLaunchKernelGGL(spmm_step_kernel, dim3(NROWS / 4), dim3(256), 0, stream,
                       accbuf[1], bufH, cnt, dis, colidx, qf, zstate, 0,
                       bern + (size_t)layer * HD, HFULL, 1, 1);
  };

  run_layer(HFULL, HFULL, W0, b0, 0);                 // h0 = f(x @ W0)
  run_layer(HFULL + HD, HFULL, W1, b1, 1);            // h1 = f([x,h0] @ W1)
  run_layer(HFULL + 2 * HD, HFULL, W2, b2, 2);        // h2 = f([x,h0,h1] @ W2)

  // out = (concat(h0,h1,h2) + x) @ Wout + bout   (sumMode fuses the +x)
  hipLaunchKernelGGL(gemm_kernel, dim3(HFULL / 64, NROWS / 64), dim3(256), 0,
                     stream, HFULL, bern, HFULL, x, HFULL, 0, 1, Wout, HFULL,
                     bout, outp, HFULL);
}

// Round 2
// 381.639 us; speedup vs baseline: 2.5348x; 2.5348x over previous
//
#include <hip/hip_runtime.h>

#define KORD   10
#define MAXDEG 64
#define NB     2048        // nodes per graph
#define NROWS  16384       // 8 * 2048
#define HD     256         // hidden per conv
#define XBW    1536        // XB width: [x(768) | h0(256) | h1(256) | h2(256)]

typedef __attribute__((ext_vector_type(8))) short short8;
typedef __attribute__((ext_vector_type(4))) float f32x4;

__device__ inline unsigned short f2bf(float f) {
  union { float f; unsigned u; } v; v.f = f;
  unsigned r = v.u + 0x7fff + ((v.u >> 16) & 1);   // round-to-nearest-even
  return (unsigned short)(r >> 16);
}
__device__ inline float bf2f(unsigned short b) {
  union { unsigned u; float f; } v; v.u = ((unsigned)b) << 16;
  return v.f;
}

#define AS1 __attribute__((address_space(1)))
#define AS3 __attribute__((address_space(3)))
__device__ inline void gload16(const void* g, void* l) {
  // 16B per lane, global (per-lane addr) -> LDS (wave-uniform base + lane*16)
  __builtin_amdgcn_global_load_lds((const AS1 void*)g, (AS3 void*)l, 16, 0, 0);
}

// ---------------------------------------------------------------------------
// q[m] = [z^m] sum_k relu(coe[k]) * C(K,k)/2^K * (1-z)^k (1+z)^{K-k}
// zstate[m] = 1 iff q[j]==0 for all j>=m. Exact in fp64 for dyadic coe.
// ---------------------------------------------------------------------------
__global__ void compute_q_kernel(const float* __restrict__ coe,
                                 float* __restrict__ qf,
                                 int* __restrict__ zstate) {
  if (threadIdx.x != 0 || blockIdx.x != 0) return;
  double C[KORD + 1][KORD + 1];
  for (int i = 0; i <= KORD; ++i)
    for (int j = 0; j <= KORD; ++j) C[i][j] = 0.0;
  for (int i = 0; i <= KORD; ++i) {
    C[i][0] = 1.0;
    for (int j = 1; j <= i; ++j) C[i][j] = C[i - 1][j - 1] + C[i - 1][j];
  }
  double q[KORD + 1];
  for (int m = 0; m <= KORD; ++m) q[m] = 0.0;
  for (int k = 0; k <= KORD; ++k) {
    double t = (double)coe[k];
    if (t < 0.0) t = 0.0;
    double ck = t * C[KORD][k] / 1024.0;
    for (int m = 0; m <= KORD; ++m) {
      double s = 0.0;
      for (int j = 0; j <= k && j <= m; ++j) {
        int rem = m - j;
        if (rem <= KORD - k) {
          double term = C[k][j] * C[KORD - k][rem];
          s += (j & 1) ? -term : term;
        }
      }
      q[m] += ck * s;
    }
  }
  for (int m = 0; m <= KORD; ++m) qf[m] = (float)q[m];
  zstate[KORD + 1] = 1;
  int z = 1;
  for (int m = KORD; m >= 0; --m) {
    if (q[m] != 0.0) z = 0;
    zstate[m] = z;
  }
}

// ---------------------------------------------------------------------------
// Adjacency lists (local col ids, ushort) + degree + D^-1/2. Wave per row.
// ---------------------------------------------------------------------------
__global__ __launch_bounds__(256) void build_adj_kernel(
    const float* __restrict__ adj,
    int* __restrict__ cnt, float* __restrict__ dis,
    unsigned short* __restrict__ colidx) {
  const int wave = threadIdx.x >> 6;
  const int lane = threadIdx.x & 63;
  const int row  = blockIdx.x * 4 + wave;          // [0, NROWS)
  const float* arow = adj + (size_t)row * NB;
  unsigned short* ci = colidx + (size_t)row * MAXDEG;
  int base = 0;
  for (int c0 = 0; c0 < NB; c0 += 64) {
    float v = arow[c0 + lane];
    unsigned long long mask = __ballot(v > 0.0f);
    if (v > 0.0f) {
      int pos = base + __popcll(mask & ((1ull << lane) - 1ull));
      if (pos < MAXDEG) ci[pos] = (unsigned short)(c0 + lane);
    }
    base += __popcll(mask);
  }
  if (lane == 0) {
    cnt[row] = base > MAXDEG ? MAXDEG : base;
    dis[row] = base > 0 ? rsqrtf((float)base) : 0.0f;
  }
}

// ---------------------------------------------------------------------------
// x (fp32 [NROWS][768]) -> XB bf16 cols [0,768) of [NROWS][XBW]
// ---------------------------------------------------------------------------
__global__ __launch_bounds__(192) void xcvt_kernel(const float* __restrict__ x,
                                                   unsigned short* __restrict__ XB) {
  const int r = blockIdx.x;
  const int c = threadIdx.x * 4;
  float4 v = *(const float4*)&x[(size_t)r * 768 + c];
  union { unsigned short s[4]; uint2 u; } o;
  o.s[0] = f2bf(v.x); o.s[1] = f2bf(v.y); o.s[2] = f2bf(v.z); o.s[3] = f2bf(v.w);
  *(uint2*)&XB[(size_t)r * XBW + c] = o.u;
}

// ---------------------------------------------------------------------------
// W [K][N] fp32 -> Wt [N][K] bf16 (32x32 LDS tile transpose). Dims %32 == 0.
// ---------------------------------------------------------------------------
__global__ __launch_bounds__(256) void wcvt_kernel(const float* __restrict__ W,
                                                   unsigned short* __restrict__ Wt,
                                                   int K, int N) {
  __shared__ float tile[32][33];
  const int k0 = blockIdx.x * 32, n0 = blockIdx.y * 32;
  const int tx = threadIdx.x & 31, ty = threadIdx.x >> 5;  // 32 x 8
#pragma unroll
  for (int i = 0; i < 4; ++i)
    tile[ty + 8 * i][tx] = W[(size_t)(k0 + ty + 8 * i) * N + n0 + tx];
  __syncthreads();
#pragma unroll
  for (int i = 0; i < 4; ++i)
    Wt[(size_t)(n0 + ty + 8 * i) * K + k0 + tx] = f2bf(tile[tx][ty + 8 * i]);
}

// ---------------------------------------------------------------------------
// bf16 MFMA GEMM: out[M=16384, N] = Amat[M,Kd] @ Wt[N,Kd]^T + bias  (fp32 out)
// Amat virtual: sumMode ? (A + A1) : A.  BM=BN=128, BK=32, 4 waves.
// LDS tiles [128 rows][32 k] bf16 with 16B-slot XOR swizzle
//   byte = row*64 + (colb ^ (((row>>1)&3)<<4))
// staged via global_load_lds x16 with pre-swizzled per-lane global source.
// ---------------------------------------------------------------------------
__global__ __launch_bounds__(256) void mfma_gemm_kernel(
    int Kd,
    const unsigned short* __restrict__ A, int lda,
    const unsigned short* __restrict__ A1, int sumMode,
    const unsigned short* __restrict__ Wt,
    const float* __restrict__ bias,
    float* __restrict__ out, int ldo) {
  __shared__ __align__(16) unsigned short Asl[128 * 32];
  __shared__ __align__(16) unsigned short Bsl[128 * 32];
  const int t    = threadIdx.x;
  const int lane = t & 63;
  const int wid  = t >> 6;
  const int wr   = wid >> 1, wc = wid & 1;
  const int row0 = blockIdx.y * 128;
  const int col0 = blockIdx.x * 128;

  f32x4 acc[4][4] = {};

  const int swz    = ((lane & 3) ^ ((lane >> 3) & 3)) * 8;  // src col elem offset
  const int subrow = lane >> 2;                             // 0..15
  const int fr = lane & 15;
  const int fq = lane >> 4;                                 // k-octet

  const int nkt = Kd >> 5;
  for (int kt = 0; kt < nkt; ++kt) {
    const int kbase = kt << 5;
#pragma unroll
    for (int i = 0; i < 4; ++i) {
      const int c = wid * 4 + i;                 // 0..15; <8 = A, else B
      if (c < 8) {
        const int r = row0 + c * 16 + subrow;
        const unsigned short* src = A + (size_t)r * lda + kbase + swz;
        if (!sumMode) {
          gload16(src, &Asl[c * 512]);
        } else {
          const unsigned short* src1 = A1 + (size_t)r * lda + kbase + swz;
          union { uint4 u; unsigned short h[8]; } va, vb, vo;
          va.u = *(const uint4*)src;
          vb.u = *(const uint4*)src1;
#pragma unroll
          for (int j = 0; j < 8; ++j)
            vo.h[j] = f2bf(bf2f(va.h[j]) + bf2f(vb.h[j]));
          *(uint4*)((char*)Asl + c * 1024 + lane * 16) = vo.u;
        }
      } else {
        const int cc = c - 8;
        const int r = col0 + cc * 16 + subrow;
        const unsigned short* src = Wt + (size_t)r * Kd + kbase + swz;
        gload16(src, &Bsl[cc * 512]);
      }
    }
    __syncthreads();

    short8 af[4], bfr[4];
#pragma unroll
    for (int m = 0; m < 4; ++m) {
      const int r = wr * 64 + m * 16 + fr;
      const int colb = (fq * 16) ^ (((r >> 1) & 3) << 4);
      af[m] = *(const short8*)((const char*)Asl + r * 64 + colb);
    }
#pragma unroll
    for (int n = 0; n < 4; ++n) {
      const int r = wc * 64 + n * 16 + fr;
      const int colb = (fq * 16) ^ (((r >> 1) & 3) << 4);
      bfr[n] = *(const short8*)((const char*)Bsl + r * 64 + colb);
    }
#pragma unroll
    for (int m = 0; m < 4; ++m)
#pragma unroll
      for (int n = 0; n < 4; ++n)
        acc[m][n] = __builtin_amdgcn_mfma_f32_16x16x32_bf16(af[m], bfr[n],
                                                            acc[m][n], 0, 0, 0);
    __syncthreads();
  }

  // epilogue: C/D layout col = lane&15, row = (lane>>4)*4 + reg
#pragma unroll
  for (int n = 0; n < 4; ++n) {
    const int col = col0 + wc * 64 + n * 16 + fr;
    const float bv = bias[col];
#pragma unroll
    for (int m = 0; m < 4; ++m) {
      const int rbase = row0 + wr * 64 + m * 16 + fq * 4;
#pragma unroll
      for (int r = 0; r < 4; ++r)
        out[(size_t)(rbase + r) * ldo + col] = acc[m][n][r] + bv;
    }
  }
}

// ---------------------------------------------------------------------------
// Fused Horner: all K+1 steps for one (graph, 4-channel slab) in one block.
// acc ping-pong in LDS (2048 x 4 fp32 x2 = 64KB), dis/cnt staged (16KB).
// Step m: nxt = Ahat @ cur + q[m]*h ; final step relu+bf16 -> XB slice.
// zstate skipping identical to the unfused version.
// ---------------------------------------------------------------------------
__global__ __launch_bounds__(256, 1) void horner_kernel(
    const float* __restrict__ h,                 // [NROWS][HD]
    const int* __restrict__ cnt, const float* __restrict__ dis,
    const unsigned short* __restrict__ colidx,
    const float* __restrict__ qf, const int* __restrict__ zstate,
    unsigned short* __restrict__ XB, int layer) {
  __shared__ float accA[NB * 4];
  __shared__ float accB[NB * 4];
  __shared__ float dls[NB];
  __shared__ int   cls[NB];
  const int blk = blockIdx.x;                    // 512 = 8 graphs * 64 slabs
  const int b   = blk >> 6;
  const int ch0 = (blk & 63) * 4;
  const int t   = threadIdx.x;
  const size_t rowbase = (size_t)b * NB;
  for (int r = t; r < NB; r += 256) {
    dls[r] = dis[rowbase + r];
    cls[r] = cnt[rowbase + r];
  }
  __syncthreads();
  float* cur = accA;
  float* nxt = accB;
  const int ch = t & 3;
  for (int m = KORD; m >= 0; --m) {
    if (m == 0 || !zstate[m]) {
      const float qm = qf[m];
      const int gather = !zstate[m + 1];
      for (int r = t >> 2; r < NB; r += 64) {
        float s = 0.f;
        if (gather) {
          const int deg = cls[r];
          const float di = dls[r];
          const unsigned short* ci = colidx + (rowbase + r) * MAXDEG;
          for (int e = 0; e < deg; ++e) {
            const int nb = ci[e];
            s += di * dls[nb] * cur[nb * 4 + ch];
          }
        }
        if (qm != 0.f) s += qm * h[(rowbase + r) * HD + ch0 + ch];
        if (m == 0)
          XB[(rowbase + r) * XBW + 768 + layer * HD + ch0 + ch] =
              f2bf(fmaxf(s, 0.f));
        else
          nxt[r * 4 + ch] = s;
      }
    }
    __syncthreads();
    float* tp = cur; cur = nxt; nxt = tp;
  }
}

// ---------------------------------------------------------------------------
extern "C" void kernel_launch(void* const* d_in, const int* in_sizes, int n_in,
                              void* d_out, int out_size, void* d_ws, size_t ws_size,
                              hipStream_t stream) {
  const float* adj  = (const float*)d_in[0];
  const float* x    = (const float*)d_in[1];
  const float* coe  = (const float*)d_in[2];
  const float* W0   = (const float*)d_in[3];
  const float* b0   = (const float*)d_in[4];
  const float* W1   = (const float*)d_in[5];
  const float* b1   = (const float*)d_in[6];
  const float* W2   = (const float*)d_in[7];
  const float* b2   = (const float*)d_in[8];
  const float* Wout = (const float*)d_in[9];
  const float* bout = (const float*)d_in[10];
  float* outp = (float*)d_out;

  // bufH (GEMM output, fp32 [NROWS][HD] = 16MB) lives in d_out; dead by the
  // time the final GEMM overwrites d_out.
  float* bufH = outp;

  char* ws = (char*)d_ws;
  float* qf     = (float*)ws;                                   // 256 B
  int*   zstate = (int*)(ws + 256);                             // 256 B
  int*   cnt    = (int*)(ws + 512);                             // 64 KB
  float* dis    = (float*)(ws + 512 + 65536);                   // 64 KB
  unsigned short* colidx = (unsigned short*)(ws + 512 + 131072);          // 2 MB
  unsigned short* XB     = (unsigned short*)(ws + 512 + 131072 + 2097152);// 48 MB
  unsigned short* Wt0 = XB + (size_t)NROWS * XBW;
  unsigned short* Wt1 = Wt0 + 768 * 256;
  unsigned short* Wt2 = Wt1 + 1024 * 256;
  unsigned short* WtO = Wt2 + 1280 * 256;
  // total ws use ~= 53 MB

  hipLaunchKernelGGL(compute_q_kernel, dim3(1), dim3(64), 0, stream,
                     coe, qf, zstate);
  hipLaunchKernelGGL(build_adj_kernel, dim3(NROWS / 4), dim3(256), 0, stream,
                     adj, cnt, dis, colidx);
  hipLaunchKernelGGL(xcvt_kernel, dim3(NROWS), dim3(192), 0, stream, x, XB);
  hipLaunchKernelGGL(wcvt_kernel, dim3(24, 8), dim3(256), 0, stream, W0, Wt0, 768, 256);
  hipLaunchKernelGGL(wcvt_kernel, dim3(32, 8), dim3(256), 0, stream, W1, Wt1, 1024, 256);
  hipLaunchKernelGGL(wcvt_kernel, dim3(40, 8), dim3(256), 0, stream, W2, Wt2, 1280, 256);
  hipLaunchKernelGGL(wcvt_kernel, dim3(24, 24), dim3(256), 0, stream, Wout, WtO, 768, 768);

  // layer l: h = [x|h0|..] @ Wl + bl  (bf16 MFMA) ; then fused Horner -> XB
  auto layer = [&](int Kd, const unsigned short* Wt, const float* bias, int l) {
    hipLaunchKernelGGL(mfma_gemm_kernel, dim3(2, 128), dim3(256), 0, stream,
                       Kd, XB, XBW, XB, 0, Wt, bias, bufH, HD);
    hipLaunchKernelGGL(horner_kernel, dim3(512), dim3(256), 0, stream,
                       bufH, cnt, dis, colidx, qf, zstate, XB, l);
  };
  layer(768,  Wt0, b0, 0);
  layer(1024, Wt1, b1, 1);
  layer(1280, Wt2, b2, 2);

  // out = (x + [h0|h1|h2]) @ Wout + bout  (sumMode fuses the add)
  hipLaunchKernelGGL(mfma_gemm_kernel, dim3(6, 128), dim3(256), 0, stream,
                     768, XB, XBW, XB + 768, 1, WtO, bout, outp, 768);
}

// Round 3
// 324.953 us; speedup vs baseline: 2.9770x; 1.1744x over previous
//
#include <hip/hip_runtime.h>

#define KORD   10
#define MAXDEG 64
#define NB     2048        // nodes per graph
#define NROWS  16384       // 8 * 2048
#define HD     256         // hidden per conv
#define XBW    1536        // XB width: [x(768) | h0(256) | h1(256) | h2(256)]

typedef __attribute__((ext_vector_type(8))) short short8;
typedef __attribute__((ext_vector_type(4))) float f32x4;

__device__ inline unsigned short f2bf(float f) {
  union { float f; unsigned u; } v; v.f = f;
  unsigned r = v.u + 0x7fff + ((v.u >> 16) & 1);   // round-to-nearest-even
  return (unsigned short)(r >> 16);
}
__device__ inline float bf2f(unsigned short b) {
  union { unsigned u; float f; } v; v.u = ((unsigned)b) << 16;
  return v.f;
}

#define AS1 __attribute__((address_space(1)))
#define AS3 __attribute__((address_space(3)))
__device__ inline void gload16(const void* g, void* l) {
  // 16B per lane, global (per-lane addr) -> LDS (wave-uniform base + lane*16)
  __builtin_amdgcn_global_load_lds((const AS1 void*)g, (AS3 void*)l, 16, 0, 0);
}

// ---------------------------------------------------------------------------
// q[m] = [z^m] sum_k relu(coe[k]) * C(K,k)/2^K * (1-z)^k (1+z)^{K-k}
// zstate[m] = 1 iff q[j]==0 for all j>=m. Exact in fp64 for dyadic coe.
// ---------------------------------------------------------------------------
__global__ void compute_q_kernel(const float* __restrict__ coe,
                                 float* __restrict__ qf,
                                 int* __restrict__ zstate) {
  if (threadIdx.x != 0 || blockIdx.x != 0) return;
  double C[KORD + 1][KORD + 1];
  for (int i = 0; i <= KORD; ++i)
    for (int j = 0; j <= KORD; ++j) C[i][j] = 0.0;
  for (int i = 0; i <= KORD; ++i) {
    C[i][0] = 1.0;
    for (int j = 1; j <= i; ++j) C[i][j] = C[i - 1][j - 1] + C[i - 1][j];
  }
  double q[KORD + 1];
  for (int m = 0; m <= KORD; ++m) q[m] = 0.0;
  for (int k = 0; k <= KORD; ++k) {
    double t = (double)coe[k];
    if (t < 0.0) t = 0.0;
    double ck = t * C[KORD][k] / 1024.0;
    for (int m = 0; m <= KORD; ++m) {
      double s = 0.0;
      for (int j = 0; j <= k && j <= m; ++j) {
        int rem = m - j;
        if (rem <= KORD - k) {
          double term = C[k][j] * C[KORD - k][rem];
          s += (j & 1) ? -term : term;
        }
      }
      q[m] += ck * s;
    }
  }
  for (int m = 0; m <= KORD; ++m) qf[m] = (float)q[m];
  zstate[KORD + 1] = 1;
  int z = 1;
  for (int m = KORD; m >= 0; --m) {
    if (q[m] != 0.0) z = 0;
    zstate[m] = z;
  }
}

// ---------------------------------------------------------------------------
// Adjacency lists (local col ids, ushort) + degree + D^-1/2. Wave per row.
// ---------------------------------------------------------------------------
__global__ __launch_bounds__(256) void build_adj_kernel(
    const float* __restrict__ adj,
    int* __restrict__ cnt, float* __restrict__ dis,
    unsigned short* __restrict__ colidx) {
  const int wave = threadIdx.x >> 6;
  const int lane = threadIdx.x & 63;
  const int row  = blockIdx.x * 4 + wave;          // [0, NROWS)
  const float* arow = adj + (size_t)row * NB;
  unsigned short* ci = colidx + (size_t)row * MAXDEG;
  int base = 0;
  for (int c0 = 0; c0 < NB; c0 += 64) {
    float v = arow[c0 + lane];
    unsigned long long mask = __ballot(v > 0.0f);
    if (v > 0.0f) {
      int pos = base + __popcll(mask & ((1ull << lane) - 1ull));
      if (pos < MAXDEG) ci[pos] = (unsigned short)(c0 + lane);
    }
    base += __popcll(mask);
  }
  if (lane == 0) {
    cnt[row] = base > MAXDEG ? MAXDEG : base;
    dis[row] = base > 0 ? rsqrtf((float)base) : 0.0f;
  }
}

// ---------------------------------------------------------------------------
// x (fp32 [NROWS][768]) -> XB bf16 cols [0,768) of [NROWS][XBW]
// ---------------------------------------------------------------------------
__global__ __launch_bounds__(192) void xcvt_kernel(const float* __restrict__ x,
                                                   unsigned short* __restrict__ XB) {
  const int r = blockIdx.x;
  const int c = threadIdx.x * 4;
  float4 v = *(const float4*)&x[(size_t)r * 768 + c];
  union { unsigned short s[4]; uint2 u; } o;
  o.s[0] = f2bf(v.x); o.s[1] = f2bf(v.y); o.s[2] = f2bf(v.z); o.s[3] = f2bf(v.w);
  *(uint2*)&XB[(size_t)r * XBW + c] = o.u;
}

// ---------------------------------------------------------------------------
// W [K][N] fp32 -> Wt rows n: Wt[n*ldt + koff + k] = bf16(W[k][n]).
// 32x32 LDS tile transpose. Dims %32 == 0.
// ---------------------------------------------------------------------------
__global__ __launch_bounds__(256) void wcvt_kernel(const float* __restrict__ W,
                                                   unsigned short* __restrict__ Wt,
                                                   int K, int N, int ldt, int koff) {
  __shared__ float tile[32][33];
  const int k0 = blockIdx.x * 32, n0 = blockIdx.y * 32;
  const int tx = threadIdx.x & 31, ty = threadIdx.x >> 5;  // 32 x 8
#pragma unroll
  for (int i = 0; i < 4; ++i)
    tile[ty + 8 * i][tx] = W[(size_t)(k0 + ty + 8 * i) * N + n0 + tx];
  __syncthreads();
#pragma unroll
  for (int i = 0; i < 4; ++i)
    Wt[(size_t)(n0 + ty + 8 * i) * ldt + koff + k0 + tx] = f2bf(tile[tx][ty + 8 * i]);
}

// ---------------------------------------------------------------------------
// bf16 MFMA GEMM: out[M=16384, N] = A[M,Kd] @ Wt[N,Kd]^T + bias
// BM=BN=128, BK=32, 4 waves, LDS double-buffered, ONE barrier per K-step
// (stage(kt+1) issued before compute(kt); barrier drains vmcnt+lgkm).
// 16B-slot XOR swizzle on LDS (pre-swizzled global source, swizzled read).
// Bijective XCD chunk swizzle (requires nwg % 8 == 0) for L2 locality.
// Epilogue: outB != 0 -> bf16 store, else fp32.
// ---------------------------------------------------------------------------
__global__ __launch_bounds__(256) void mfma_gemm_kernel(
    int Kd,
    const unsigned short* __restrict__ A, int lda,
    const unsigned short* __restrict__ Wt, int ldw,
    const float* __restrict__ bias,
    float* __restrict__ outF, unsigned short* __restrict__ outB, int ldo) {
  __shared__ __align__(16) unsigned short Asl[2][128 * 32];
  __shared__ __align__(16) unsigned short Bsl[2][128 * 32];
  const int t    = threadIdx.x;
  const int lane = t & 63;
  const int wid  = t >> 6;
  const int wr   = wid >> 1, wc = wid & 1;

  // XCD-aware chunked block swizzle: each XCD gets a contiguous row-major chunk
  const int gx  = gridDim.x;
  const int nwg = gx * gridDim.y;
  int bid = blockIdx.y * gx + blockIdx.x;
  if ((nwg & 7) == 0) bid = (bid & 7) * (nwg >> 3) + (bid >> 3);
  const int row0 = (bid / gx) * 128;
  const int col0 = (bid % gx) * 128;

  f32x4 acc[4][4] = {};

  const int swz    = ((lane & 3) ^ ((lane >> 3) & 3)) * 8;  // src col elem offset
  const int subrow = lane >> 2;                             // 0..15
  const int fr = lane & 15;
  const int fq = lane >> 4;                                 // k-octet

  const int nkt = Kd >> 5;

  auto stage = [&](int kt, int pb) {
    const int kbase = kt << 5;
#pragma unroll
    for (int i = 0; i < 4; ++i) {
      const int c = wid * 4 + i;                 // 0..15; <8 = A, else B
      if (c < 8) {
        const int r = row0 + c * 16 + subrow;
        gload16(A + (size_t)r * lda + kbase + swz, &Asl[pb][c * 512]);
      } else {
        const int cc = c - 8;
        const int r = col0 + cc * 16 + subrow;
        gload16(Wt + (size_t)r * ldw + kbase + swz, &Bsl[pb][cc * 512]);
      }
    }
  };

  stage(0, 0);
  __syncthreads();

  for (int kt = 0; kt < nkt; ++kt) {
    const int pb = kt & 1;
    if (kt + 1 < nkt) stage(kt + 1, pb ^ 1);

    short8 af[4], bfr[4];
#pragma unroll
    for (int m = 0; m < 4; ++m) {
      const int r = wr * 64 + m * 16 + fr;
      const int colb = (fq * 16) ^ (((r >> 1) & 3) << 4);
      af[m] = *(const short8*)((const char*)&Asl[pb][0] + r * 64 + colb);
    }
#pragma unroll
    for (int n = 0; n < 4; ++n) {
      const int r = wc * 64 + n * 16 + fr;
      const int colb = (fq * 16) ^ (((r >> 1) & 3) << 4);
      bfr[n] = *(const short8*)((const char*)&Bsl[pb][0] + r * 64 + colb);
    }
#pragma unroll
    for (int m = 0; m < 4; ++m)
#pragma unroll
      for (int n = 0; n < 4; ++n)
        acc[m][n] = __builtin_amdgcn_mfma_f32_16x16x32_bf16(af[m], bfr[n],
                                                            acc[m][n], 0, 0, 0);
    __syncthreads();   // drains vmcnt (next-tile stage) + lgkm (our ds_reads)
  }

  // epilogue: C/D layout col = lane&15, row = (lane>>4)*4 + reg
#pragma unroll
  for (int n = 0; n < 4; ++n) {
    const int col = col0 + wc * 64 + n * 16 + fr;
    const float bv = bias[col];
#pragma unroll
    for (int m = 0; m < 4; ++m) {
      const int rbase = row0 + wr * 64 + m * 16 + fq * 4;
#pragma unroll
      for (int r = 0; r < 4; ++r) {
        const float v = acc[m][n][r] + bv;
        if (outB) outB[(size_t)(rbase + r) * ldo + col] = f2bf(v);
        else      outF[(size_t)(rbase + r) * ldo + col] = v;
      }
    }
  }
}

// ---------------------------------------------------------------------------
// Fused Horner: all K+1 steps for one (graph, 4-channel slab) in one block.
// acc ping-pong in LDS, dis/cnt staged. h is bf16.
// Step m: nxt = Ahat @ cur + q[m]*h ; final step relu+bf16 -> XB slice.
// ---------------------------------------------------------------------------
__global__ __launch_bounds__(256, 1) void horner_kernel(
    const unsigned short* __restrict__ h,        // [NROWS][HD] bf16
    const int* __restrict__ cnt, const float* __restrict__ dis,
    const unsigned short* __restrict__ colidx,
    const float* __restrict__ qf, const int* __restrict__ zstate,
    unsigned short* __restrict__ XB, int layer) {
  __shared__ float accA[NB * 4];
  __shared__ float accB[NB * 4];
  __shared__ float dls[NB];
  __shared__ int   cls[NB];
  const int blk = blockIdx.x;                    // 512 = 8 graphs * 64 slabs
  const int b   = blk >> 6;
  const int ch0 = (blk & 63) * 4;
  const int t   = threadIdx.x;
  const size_t rowbase = (size_t)b * NB;
  for (int r = t; r < NB; r += 256) {
    dls[r] = dis[rowbase + r];
    cls[r] = cnt[rowbase + r];
  }
  __syncthreads();
  float* cur = accA;
  float* nxt = accB;
  const int ch = t & 3;
  for (int m = KORD; m >= 0; --m) {
    if (m == 0 || !zstate[m]) {
      const float qm = qf[m];
      const int gather = !zstate[m + 1];
      for (int r = t >> 2; r < NB; r += 64) {
        float s = 0.f;
        if (gather) {
          const int deg = cls[r];
          const float di = dls[r];
          const unsigned short* ci = colidx + (rowbase + r) * MAXDEG;
          for (int e = 0; e < deg; ++e) {
            const int nb = ci[e];
            s += di * dls[nb] * cur[nb * 4 + ch];
          }
        }
        if (qm != 0.f) s += qm * bf2f(h[(rowbase + r) * HD + ch0 + ch]);
        if (m == 0)
          XB[(rowbase + r) * XBW + 768 + layer * HD + ch0 + ch] =
              f2bf(fmaxf(s, 0.f));
        else
          nxt[r * 4 + ch] = s;
      }
    }
    __syncthreads();
    float* tp = cur; cur = nxt; nxt = tp;
  }
}

// ---------------------------------------------------------------------------
extern "C" void kernel_launch(void* const* d_in, const int* in_sizes, int n_in,
                              void* d_out, int out_size, void* d_ws, size_t ws_size,
                              hipStream_t stream) {
  const float* adj  = (const float*)d_in[0];
  const float* x    = (const float*)d_in[1];
  const float* coe  = (const float*)d_in[2];
  const float* W0   = (const float*)d_in[3];
  const float* b0   = (const float*)d_in[4];
  const float* W1   = (const float*)d_in[5];
  const float* b1   = (const float*)d_in[6];
  const float* W2   = (const float*)d_in[7];
  const float* b2   = (const float*)d_in[8];
  const float* Wout = (const float*)d_in[9];
  const float* bout = (const float*)d_in[10];
  float* outp = (float*)d_out;

  // bufH (GEMM output, bf16 [NROWS][HD] = 8MB) lives in d_out; dead by the
  // time the final GEMM overwrites d_out.
  unsigned short* bufH = (unsigned short*)outp;

  char* ws = (char*)d_ws;
  float* qf     = (float*)ws;                                   // 256 B
  int*   zstate = (int*)(ws + 256);                             // 256 B
  int*   cnt    = (int*)(ws + 512);                             // 64 KB
  float* dis    = (float*)(ws + 512 + 65536);                   // 64 KB
  unsigned short* colidx = (unsigned short*)(ws + 512 + 131072);          // 2 MB
  unsigned short* XB     = (unsigned short*)(ws + 512 + 131072 + 2097152);// 48 MB
  unsigned short* Wt0 = XB + (size_t)NROWS * XBW;               // [256][768]
  unsigned short* Wt1 = Wt0 + 256 * 768;                        // [256][1024]
  unsigned short* Wt2 = Wt1 + 256 * 1024;                       // [256][1280]
  unsigned short* WtO = Wt2 + 256 * 1280;                       // [768][1536] (Wout twice in K)
  // total ws use ~= 56 MB

  hipLaunchKernelGGL(compute_q_kernel, dim3(1), dim3(64), 0, stream,
                     coe, qf, zstate);
  hipLaunchKernelGGL(build_adj_kernel, dim3(NROWS / 4), dim3(256), 0, stream,
                     adj, cnt, dis, colidx);
  hipLaunchKernelGGL(xcvt_kernel, dim3(NROWS), dim3(192), 0, stream, x, XB);
  hipLaunchKernelGGL(wcvt_kernel, dim3(24, 8), dim3(256), 0, stream, W0, Wt0, 768, 256, 768, 0);
  hipLaunchKernelGGL(wcvt_kernel, dim3(32, 8), dim3(256), 0, stream, W1, Wt1, 1024, 256, 1024, 0);
  hipLaunchKernelGGL(wcvt_kernel, dim3(40, 8), dim3(256), 0, stream, W2, Wt2, 1280, 256, 1280, 0);
  hipLaunchKernelGGL(wcvt_kernel, dim3(24, 24), dim3(256), 0, stream, Wout, WtO, 768, 768, 1536, 0);
  hipLaunchKernelGGL(wcvt_kernel, dim3(24, 24), dim3(256), 0, stream, Wout, WtO, 768, 768, 1536, 768);

  // layer l: h = [x|h0|..] @ Wl + bl  (bf16 MFMA) ; then fused Horner -> XB
  auto layer = [&](int Kd, const unsigned short* Wt, const float* bias, int l) {
    hipLaunchKernelGGL(mfma_gemm_kernel, dim3(2, 128), dim3(256), 0, stream,
                       Kd, XB, XBW, Wt, Kd, bias, (float*)nullptr, bufH, HD);
    hipLaunchKernelGGL(horner_kernel, dim3(512), dim3(256), 0, stream,
                       bufH, cnt, dis, colidx, qf, zstate, XB, l);
  };
  layer(768,  Wt0, b0, 0);
  layer(1024, Wt1, b1, 1);
  layer(1280, Wt2, b2, 2);

  // out = [x | h0h1h2] @ [Wout ; Wout] + bout   (K=1536; algebraic sum fusion)
  hipLaunchKernelGGL(mfma_gemm_kernel, dim3(6, 128), dim3(256), 0, stream,
                     1536, XB, XBW, WtO, 1536, bout, outp,
                     (unsigned short*)nullptr, 768);
}

// Round 4
// 293.358 us; speedup vs baseline: 3.2976x; 1.1077x over previous
//
#include <hip/hip_runtime.h>

#define KORD   10
#define MAXDEG 64
#define NB     2048        // nodes per graph
#define NROWS  16384       // 8 * 2048
#define HD     256         // hidden per conv
#define XBW    1536        // XB width: [x(768) | h0(256) | h1(256) | h2(256)]

typedef __attribute__((ext_vector_type(8))) short short8;
typedef __attribute__((ext_vector_type(4))) float f32x4;

__device__ inline unsigned short f2bf(float f) {
  union { float f; unsigned u; } v; v.f = f;
  unsigned r = v.u + 0x7fff + ((v.u >> 16) & 1);   // round-to-nearest-even
  return (unsigned short)(r >> 16);
}
__device__ inline float bf2f(unsigned short b) {
  union { unsigned u; float f; } v; v.u = ((unsigned)b) << 16;
  return v.f;
}

#define AS1 __attribute__((address_space(1)))
#define AS3 __attribute__((address_space(3)))
__device__ inline void gload16(const void* g, void* l) {
  // 16B per lane, global (per-lane addr) -> LDS (wave-uniform base + lane*16)
  __builtin_amdgcn_global_load_lds((const AS1 void*)g, (AS3 void*)l, 16, 0, 0);
}

// ---------------------------------------------------------------------------
// Fused prep: one dispatch, branch by block range.
//   [0,4096)      build_adj: adjacency lists + deg + D^-1/2 (wave per row)
//   [4096,6144)   xcvt: x fp32 -> XB bf16 cols [0,768)
//   [6144,8064)   wcvt x5: W [K][N] fp32 -> Wt [N][ldt] bf16 transposed
//   [8064]        compute_q: monomial coeffs q[m] + zero-state flags
// ---------------------------------------------------------------------------
__global__ __launch_bounds__(256) void prep_kernel(
    const float* __restrict__ adj, const float* __restrict__ x,
    const float* __restrict__ coe,
    const float* __restrict__ W0, const float* __restrict__ W1,
    const float* __restrict__ W2, const float* __restrict__ Wout,
    int* __restrict__ cnt, float* __restrict__ dis,
    unsigned short* __restrict__ colidx,
    unsigned short* __restrict__ XB,
    unsigned short* __restrict__ Wt0, unsigned short* __restrict__ Wt1,
    unsigned short* __restrict__ Wt2, unsigned short* __restrict__ WtO,
    float* __restrict__ qf, int* __restrict__ zstate) {
  __shared__ float tile[32][33];
  const int blk = blockIdx.x;
  const int t = threadIdx.x;

  if (blk < 4096) {                       // ---- build_adj ----
    const int wave = t >> 6;
    const int lane = t & 63;
    const int row  = blk * 4 + wave;
    const float* arow = adj + (size_t)row * NB;
    unsigned short* ci = colidx + (size_t)row * MAXDEG;
    int base = 0;
    for (int c0 = 0; c0 < NB; c0 += 64) {
      float v = arow[c0 + lane];
      unsigned long long mask = __ballot(v > 0.0f);
      if (v > 0.0f) {
        int pos = base + __popcll(mask & ((1ull << lane) - 1ull));
        if (pos < MAXDEG) ci[pos] = (unsigned short)(c0 + lane);
      }
      base += __popcll(mask);
    }
    if (lane == 0) {
      cnt[row] = base > MAXDEG ? MAXDEG : base;
      dis[row] = base > 0 ? rsqrtf((float)base) : 0.0f;
    }
    return;
  }

  if (blk < 6144) {                       // ---- xcvt: 8 rows per block ----
    const int r0 = (blk - 4096) * 8;
    for (int i = t; i < 8 * 192; i += 256) {
      const int r = r0 + (i / 192);
      const int c = (i % 192) * 4;
      float4 v = *(const float4*)&x[(size_t)r * 768 + c];
      union { unsigned short s[4]; uint2 u; } o;
      o.s[0] = f2bf(v.x); o.s[1] = f2bf(v.y);
      o.s[2] = f2bf(v.z); o.s[3] = f2bf(v.w);
      *(uint2*)&XB[(size_t)r * XBW + c] = o.u;
    }
    return;
  }

  if (blk < 8064) {                       // ---- wcvt (5 jobs) ----
    const float* W; unsigned short* Wt; int N, ldt, koff, gx, lb;
    int b = blk - 6144;
    if (b < 192)       { W = W0;   Wt = Wt0; N = 256; ldt = 768;  koff = 0;   gx = 24; lb = b; }
    else if (b < 448)  { W = W1;   Wt = Wt1; N = 256; ldt = 1024; koff = 0;   gx = 32; lb = b - 192; }
    else if (b < 768)  { W = W2;   Wt = Wt2; N = 256; ldt = 1280; koff = 0;   gx = 40; lb = b - 448; }
    else if (b < 1344) { W = Wout; Wt = WtO; N = 768; ldt = 1536; koff = 0;   gx = 24; lb = b - 768; }
    else               { W = Wout; Wt = WtO; N = 768; ldt = 1536; koff = 768; gx = 24; lb = b - 1344; }
    const int k0 = (lb % gx) * 32, n0 = (lb / gx) * 32;
    const int tx = t & 31, ty = t >> 5;
#pragma unroll
    for (int i = 0; i < 4; ++i)
      tile[ty + 8 * i][tx] = W[(size_t)(k0 + ty + 8 * i) * N + n0 + tx];
    __syncthreads();
#pragma unroll
    for (int i = 0; i < 4; ++i)
      Wt[(size_t)(n0 + ty + 8 * i) * ldt + koff + k0 + tx] =
          f2bf(tile[tx][ty + 8 * i]);
    return;
  }

  // ---- compute_q (one block, one thread) ----
  if (t != 0) return;
  double C[KORD + 1][KORD + 1];
  for (int i = 0; i <= KORD; ++i)
    for (int j = 0; j <= KORD; ++j) C[i][j] = 0.0;
  for (int i = 0; i <= KORD; ++i) {
    C[i][0] = 1.0;
    for (int j = 1; j <= i; ++j) C[i][j] = C[i - 1][j - 1] + C[i - 1][j];
  }
  double q[KORD + 1];
  for (int m = 0; m <= KORD; ++m) q[m] = 0.0;
  for (int k = 0; k <= KORD; ++k) {
    double tt = (double)coe[k];
    if (tt < 0.0) tt = 0.0;
    double ck = tt * C[KORD][k] / 1024.0;
    for (int m = 0; m <= KORD; ++m) {
      double s = 0.0;
      for (int j = 0; j <= k && j <= m; ++j) {
        int rem = m - j;
        if (rem <= KORD - k) {
          double term = C[k][j] * C[KORD - k][rem];
          s += (j & 1) ? -term : term;
        }
      }
      q[m] += ck * s;
    }
  }
  for (int m = 0; m <= KORD; ++m) qf[m] = (float)q[m];
  zstate[KORD + 1] = 1;
  int z = 1;
  for (int m = KORD; m >= 0; --m) {
    if (q[m] != 0.0) z = 0;
    zstate[m] = z;
  }
}

// ---------------------------------------------------------------------------
// bf16 MFMA GEMM: out[M=16384, N] = A[M,Kd] @ Wt[N,Kd]^T + bias
// BM=BN=128, BK=32, 4 waves. 4-buffer LDS ring, counted vmcnt (never 0 in
// steady state), raw s_barrier: ONE barrier per K-step, 2 stages in flight.
// 16B-slot XOR swizzle (pre-swizzled global src + swizzled ds_read).
// Bijective XCD chunk swizzle. Epilogue: outB!=0 -> bf16 else fp32.
// ---------------------------------------------------------------------------
__global__ __launch_bounds__(256) void mfma_gemm_kernel(
    int Kd,
    const unsigned short* __restrict__ A, int lda,
    const unsigned short* __restrict__ Wt, int ldw,
    const float* __restrict__ bias,
    float* __restrict__ outF, unsigned short* __restrict__ outB, int ldo) {
  __shared__ __align__(16) unsigned short Asl[4][128 * 32];
  __shared__ __align__(16) unsigned short Bsl[4][128 * 32];
  const int t    = threadIdx.x;
  const int lane = t & 63;
  const int wid  = t >> 6;
  const int wr   = wid >> 1, wc = wid & 1;

  const int gx  = gridDim.x;
  const int nwg = gx * gridDim.y;
  int bid = blockIdx.y * gx + blockIdx.x;
  if ((nwg & 7) == 0) bid = (bid & 7) * (nwg >> 3) + (bid >> 3);
  const int row0 = (bid / gx) * 128;
  const int col0 = (bid % gx) * 128;

  f32x4 acc[4][4] = {};

  const int swz    = ((lane & 3) ^ ((lane >> 3) & 3)) * 8;
  const int subrow = lane >> 2;
  const int fr = lane & 15;
  const int fq = lane >> 4;

  const int nkt = Kd >> 5;

  auto stage = [&](int kt, int pb) {
    const int kbase = kt << 5;
#pragma unroll
    for (int i = 0; i < 4; ++i) {
      const int c = wid * 4 + i;                 // 0..15; <8 = A, else B
      if (c < 8) {
        const int r = row0 + c * 16 + subrow;
        gload16(A + (size_t)r * lda + kbase + swz, &Asl[pb][c * 512]);
      } else {
        const int cc = c - 8;
        const int r = col0 + cc * 16 + subrow;
        gload16(Wt + (size_t)r * ldw + kbase + swz, &Bsl[pb][cc * 512]);
      }
    }
  };

  stage(0, 0);
  if (nkt > 1) stage(1, 1);

  for (int kt = 0; kt < nkt; ++kt) {
    const int pb = kt & 3;
    if (kt + 2 < nkt) {
      stage(kt + 2, (kt + 2) & 3);
      asm volatile("s_waitcnt vmcnt(8)" ::: "memory");
    } else if (kt + 1 < nkt) {
      asm volatile("s_waitcnt vmcnt(4)" ::: "memory");
    } else {
      asm volatile("s_waitcnt vmcnt(0)" ::: "memory");
    }
    __builtin_amdgcn_s_barrier();
    asm volatile("" ::: "memory");

    short8 af[4], bfr[4];
#pragma unroll
    for (int m = 0; m < 4; ++m) {
      const int r = wr * 64 + m * 16 + fr;
      const int colb = (fq * 16) ^ (((r >> 1) & 3) << 4);
      af[m] = *(const short8*)((const char*)&Asl[pb][0] + r * 64 + colb);
    }
#pragma unroll
    for (int n = 0; n < 4; ++n) {
      const int r = wc * 64 + n * 16 + fr;
      const int colb = (fq * 16) ^ (((r >> 1) & 3) << 4);
      bfr[n] = *(const short8*)((const char*)&Bsl[pb][0] + r * 64 + colb);
    }
    __builtin_amdgcn_s_setprio(1);
#pragma unroll
    for (int m = 0; m < 4; ++m)
#pragma unroll
      for (int n = 0; n < 4; ++n)
        acc[m][n] = __builtin_amdgcn_mfma_f32_16x16x32_bf16(af[m], bfr[n],
                                                            acc[m][n], 0, 0, 0);
    __builtin_amdgcn_s_setprio(0);
  }

  // epilogue: C/D layout col = lane&15, row = (lane>>4)*4 + reg
#pragma unroll
  for (int n = 0; n < 4; ++n) {
    const int col = col0 + wc * 64 + n * 16 + fr;
    const float bv = bias[col];
#pragma unroll
    for (int m = 0; m < 4; ++m) {
      const int rbase = row0 + wr * 64 + m * 16 + fq * 4;
#pragma unroll
      for (int r = 0; r < 4; ++r) {
        const float v = acc[m][n][r] + bv;
        if (outB) outB[(size_t)(rbase + r) * ldo + col] = f2bf(v);
        else      outF[(size_t)(rbase + r) * ldo + col] = v;
      }
    }
  }
}

// ---------------------------------------------------------------------------
// Fused Horner: all K+1 steps for one (graph, 4-channel slab) in one block.
// Fast path when zstate[1] (filter == q0*I): relu-copy, no LDS, no barriers.
// General path: acc ping-pong in LDS, dis/cnt staged, zstate skipping.
// ---------------------------------------------------------------------------
__global__ __launch_bounds__(256, 1) void horner_kernel(
    const unsigned short* __restrict__ h,        // [NROWS][HD] bf16
    const int* __restrict__ cnt, const float* __restrict__ dis,
    const unsigned short* __restrict__ colidx,
    const float* __restrict__ qf, const int* __restrict__ zstate,
    unsigned short* __restrict__ XB, int layer) {
  __shared__ float accA[NB * 4];
  __shared__ float accB[NB * 4];
  __shared__ float dls[NB];
  __shared__ int   cls[NB];
  const int blk = blockIdx.x;                    // 512 = 8 graphs * 64 slabs
  const int b   = blk >> 6;
  const int ch0 = (blk & 63) * 4;
  const int t   = threadIdx.x;
  const size_t rowbase = (size_t)b * NB;

  if (zstate[1]) {                               // ---- fast path ----
    const float q0 = qf[0];
    for (int r = t; r < NB; r += 256) {
      union { unsigned short s[4]; uint2 u; } iv, ov;
      iv.u = *(const uint2*)&h[(rowbase + r) * HD + ch0];
#pragma unroll
      for (int j = 0; j < 4; ++j)
        ov.s[j] = f2bf(fmaxf(q0 * bf2f(iv.s[j]), 0.f));
      *(uint2*)&XB[(rowbase + r) * XBW + 768 + layer * HD + ch0] = ov.u;
    }
    return;
  }

  for (int r = t; r < NB; r += 256) {
    dls[r] = dis[rowbase + r];
    cls[r] = cnt[rowbase + r];
  }
  __syncthreads();
  float* cur = accA;
  float* nxt = accB;
  const int ch = t & 3;
  for (int m = KORD; m >= 0; --m) {
    if (m == 0 || !zstate[m]) {
      const float qm = qf[m];
      const int gather = !zstate[m + 1];
      for (int r = t >> 2; r < NB; r += 64) {
        float s = 0.f;
        if (gather) {
          const int deg = cls[r];
          const float di = dls[r];
          const unsigned short* ci = colidx + (rowbase + r) * MAXDEG;
          for (int e = 0; e < deg; ++e) {
            const int nb = ci[e];
            s += di * dls[nb] * cur[nb * 4 + ch];
          }
        }
        if (qm != 0.f) s += qm * bf2f(h[(rowbase + r) * HD + ch0 + ch]);
        if (m == 0)
          XB[(rowbase + r) * XBW + 768 + layer * HD + ch0 + ch] =
              f2bf(fmaxf(s, 0.f));
        else
          nxt[r * 4 + ch] = s;
      }
    }
    __syncthreads();
    float* tp = cur; cur = nxt; nxt = tp;
  }
}

// ---------------------------------------------------------------------------
extern "C" void kernel_launch(void* const* d_in, const int* in_sizes, int n_in,
                              void* d_out, int out_size, void* d_ws, size_t ws_size,
                              hipStream_t stream) {
  const float* adj  = (const float*)d_in[0];
  const float* x    = (const float*)d_in[1];
  const float* coe  = (const float*)d_in[2];
  const float* W0   = (const float*)d_in[3];
  const float* b0   = (const float*)d_in[4];
  const float* W1   = (const float*)d_in[5];
  const float* b1   = (const float*)d_in[6];
  const float* W2   = (const float*)d_in[7];
  const float* b2   = (const float*)d_in[8];
  const float* Wout = (const float*)d_in[9];
  const float* bout = (const float*)d_in[10];
  float* outp = (float*)d_out;

  // bufH (GEMM output, bf16 [NROWS][HD] = 8MB) lives in d_out; dead by the
  // time the final GEMM overwrites d_out.
  unsigned short* bufH = (unsigned short*)outp;

  char* ws = (char*)d_ws;
  float* qf     = (float*)ws;                                   // 256 B
  int*   zstate = (int*)(ws + 256);                             // 256 B
  int*   cnt    = (int*)(ws + 512);                             // 64 KB
  float* dis    = (float*)(ws + 512 + 65536);                   // 64 KB
  unsigned short* colidx = (unsigned short*)(ws + 512 + 131072);          // 2 MB
  unsigned short* XB     = (unsigned short*)(ws + 512 + 131072 + 2097152);// 48 MB
  unsigned short* Wt0 = XB + (size_t)NROWS * XBW;               // [256][768]
  unsigned short* Wt1 = Wt0 + 256 * 768;                        // [256][1024]
  unsigned short* Wt2 = Wt1 + 256 * 1024;                       // [256][1280]
  unsigned short* WtO = Wt2 + 256 * 1280;                       // [768][1536]

  hipLaunchKernelGGL(prep_kernel, dim3(8065), dim3(256), 0, stream,
                     adj, x, coe, W0, W1, W2, Wout,
                     cnt, dis, colidx, XB, Wt0, Wt1, Wt2, WtO, qf, zstate);

  // layer l: h = [x|h0|..] @ Wl + bl  (bf16 MFMA) ; then fused Horner -> XB
  auto layer = [&](int Kd, const unsigned short* Wt, const float* bias, int l) {
    hipLaunchKernelGGL(mfma_gemm_kernel, dim3(2, 128), dim3(256), 0, stream,
                       Kd, XB, XBW, Wt, Kd, bias, (float*)nullptr, bufH, HD);
    hipLaunchKernelGGL(horner_kernel, dim3(512), dim3(256), 0, stream,
                       bufH, cnt, dis, colidx, qf, zstate, XB, l);
  };
  layer(768,  Wt0, b0, 0);
  layer(1024, Wt1, b1, 1);
  layer(1280, Wt2, b2, 2);

  // out = [x | h0h1h2] @ [Wout ; Wout] + bout   (K=1536; algebraic sum fusion)
  hipLaunchKernelGGL(mfma_gemm_kernel, dim3(6, 128), dim3(256), 0, stream,
                     1536, XB, XBW, WtO, 1536, bout, outp,
                     (unsigned short*)nullptr, 768);
}

// Round 5
// 245.416 us; speedup vs baseline: 3.9418x; 1.1953x over previous
//
#include <hip/hip_runtime.h>

#define KORD   10
#define MAXDEG 64
#define NB     2048        // nodes per graph
#define NROWS  16384       // 8 * 2048
#define HD     256         // hidden per conv
#define XBW    1536        // XB width: [x(768) | h0(256) | h1(256) | h2(256)]

typedef __attribute__((ext_vector_type(8))) short short8;
typedef __attribute__((ext_vector_type(4))) float f32x4;

__device__ inline unsigned short f2bf(float f) {
  union { float f; unsigned u; } v; v.f = f;
  unsigned r = v.u + 0x7fff + ((v.u >> 16) & 1);   // round-to-nearest-even
  return (unsigned short)(r >> 16);
}
__device__ inline float bf2f(unsigned short b) {
  union { unsigned u; float f; } v; v.u = ((unsigned)b) << 16;
  return v.f;
}

#define AS1 __attribute__((address_space(1)))
#define AS3 __attribute__((address_space(3)))
__device__ inline void gload16(const void* g, void* l) {
  // 16B per lane, global (per-lane addr) -> LDS (wave-uniform base + lane*16)
  __builtin_amdgcn_global_load_lds((const AS1 void*)g, (AS3 void*)l, 16, 0, 0);
}

// ---------------------------------------------------------------------------
// Fused prep: one dispatch, branch by block range.
//   [0,4096)      build_adj: adjacency lists + deg + D^-1/2 (wave per row,
//                 8 x dwordx4 row load up-front -> 8 loads in flight)
//   [4096,6144)   xcvt: x fp32 -> XB bf16 cols [0,768)
//   [6144,8064)   wcvt x5: W [K][N] fp32 -> Wt [N][ldt] bf16 transposed
//   [8064]        compute_q: monomial coeffs q[m] + zero-state flags
// ---------------------------------------------------------------------------
__global__ __launch_bounds__(256) void prep_kernel(
    const float* __restrict__ adj, const float* __restrict__ x,
    const float* __restrict__ coe,
    const float* __restrict__ W0, const float* __restrict__ W1,
    const float* __restrict__ W2, const float* __restrict__ Wout,
    int* __restrict__ cnt, float* __restrict__ dis,
    unsigned short* __restrict__ colidx,
    unsigned short* __restrict__ XB,
    unsigned short* __restrict__ Wt0, unsigned short* __restrict__ Wt1,
    unsigned short* __restrict__ Wt2, unsigned short* __restrict__ WtO,
    float* __restrict__ qf, int* __restrict__ zstate) {
  __shared__ float tile[32][33];
  const int blk = blockIdx.x;
  const int t = threadIdx.x;

  if (blk < 4096) {                       // ---- build_adj ----
    const int wave = t >> 6;
    const int lane = t & 63;
    const int row  = blk * 4 + wave;
    const float4* arow4 = (const float4*)(adj + (size_t)row * NB);
    unsigned short* ci = colidx + (size_t)row * MAXDEG;
    float4 v[8];
#pragma unroll
    for (int i = 0; i < 8; ++i) v[i] = arow4[i * 64 + lane];   // 8 loads in flight
    const unsigned long long lower = (1ull << lane) - 1ull;
    int base = 0;
#pragma unroll
    for (int i = 0; i < 8; ++i) {
      const int col = i * 256 + lane * 4;
      const int b0 = v[i].x > 0.f, b1 = v[i].y > 0.f;
      const int b2 = v[i].z > 0.f, b3 = v[i].w > 0.f;
      const unsigned long long m0 = __ballot(b0), m1 = __ballot(b1);
      const unsigned long long m2 = __ballot(b2), m3 = __ballot(b3);
      int pre = base + __popcll(m0 & lower) + __popcll(m1 & lower) +
                __popcll(m2 & lower) + __popcll(m3 & lower);
      if (b0) { if (pre < MAXDEG) ci[pre] = (unsigned short)col; ++pre; }
      if (b1) { if (pre < MAXDEG) ci[pre] = (unsigned short)(col + 1); ++pre; }
      if (b2) { if (pre < MAXDEG) ci[pre] = (unsigned short)(col + 2); ++pre; }
      if (b3) { if (pre < MAXDEG) ci[pre] = (unsigned short)(col + 3); ++pre; }
      base += __popcll(m0) + __popcll(m1) + __popcll(m2) + __popcll(m3);
    }
    if (lane == 0) {
      cnt[row] = base > MAXDEG ? MAXDEG : base;
      dis[row] = base > 0 ? rsqrtf((float)base) : 0.0f;
    }
    return;
  }

  if (blk < 6144) {                       // ---- xcvt: 8 rows per block ----
    const int r0 = (blk - 4096) * 8;
    for (int i = t; i < 8 * 192; i += 256) {
      const int r = r0 + (i / 192);
      const int c = (i % 192) * 4;
      float4 v = *(const float4*)&x[(size_t)r * 768 + c];
      union { unsigned short s[4]; uint2 u; } o;
      o.s[0] = f2bf(v.x); o.s[1] = f2bf(v.y);
      o.s[2] = f2bf(v.z); o.s[3] = f2bf(v.w);
      *(uint2*)&XB[(size_t)r * XBW + c] = o.u;
    }
    return;
  }

  if (blk < 8064) {                       // ---- wcvt (5 jobs) ----
    const float* W; unsigned short* Wt; int N, ldt, koff, gx, lb;
    int b = blk - 6144;
    if (b < 192)       { W = W0;   Wt = Wt0; N = 256; ldt = 768;  koff = 0;   gx = 24; lb = b; }
    else if (b < 448)  { W = W1;   Wt = Wt1; N = 256; ldt = 1024; koff = 0;   gx = 32; lb = b - 192; }
    else if (b < 768)  { W = W2;   Wt = Wt2; N = 256; ldt = 1280; koff = 0;   gx = 40; lb = b - 448; }
    else if (b < 1344) { W = Wout; Wt = WtO; N = 768; ldt = 1536; koff = 0;   gx = 24; lb = b - 768; }
    else               { W = Wout; Wt = WtO; N = 768; ldt = 1536; koff = 768; gx = 24; lb = b - 1344; }
    const int k0 = (lb % gx) * 32, n0 = (lb / gx) * 32;
    const int tx = t & 31, ty = t >> 5;
#pragma unroll
    for (int i = 0; i < 4; ++i)
      tile[ty + 8 * i][tx] = W[(size_t)(k0 + ty + 8 * i) * N + n0 + tx];
    __syncthreads();
#pragma unroll
    for (int i = 0; i < 4; ++i)
      Wt[(size_t)(n0 + ty + 8 * i) * ldt + koff + k0 + tx] =
          f2bf(tile[tx][ty + 8 * i]);
    return;
  }

  // ---- compute_q (one block, one thread) ----
  if (t != 0) return;
  double C[KORD + 1][KORD + 1];
  for (int i = 0; i <= KORD; ++i)
    for (int j = 0; j <= KORD; ++j) C[i][j] = 0.0;
  for (int i = 0; i <= KORD; ++i) {
    C[i][0] = 1.0;
    for (int j = 1; j <= i; ++j) C[i][j] = C[i - 1][j - 1] + C[i - 1][j];
  }
  double q[KORD + 1];
  for (int m = 0; m <= KORD; ++m) q[m] = 0.0;
  for (int k = 0; k <= KORD; ++k) {
    double tt = (double)coe[k];
    if (tt < 0.0) tt = 0.0;
    double ck = tt * C[KORD][k] / 1024.0;
    for (int m = 0; m <= KORD; ++m) {
      double s = 0.0;
      for (int j = 0; j <= k && j <= m; ++j) {
        int rem = m - j;
        if (rem <= KORD - k) {
          double term = C[k][j] * C[KORD - k][rem];
          s += (j & 1) ? -term : term;
        }
      }
      q[m] += ck * s;
    }
  }
  for (int m = 0; m <= KORD; ++m) qf[m] = (float)q[m];
  zstate[KORD + 1] = 1;
  int z = 1;
  for (int m = KORD; m >= 0; --m) {
    if (q[m] != 0.0) z = 0;
    zstate[m] = z;
  }
}

// ---------------------------------------------------------------------------
// bf16 MFMA GEMM: out[M=16384, N] = A[M,Kd] @ Wt[N,Kd]^T + bias
// BM=BN=128, BK=32, 4 waves. 4-buffer LDS ring, counted vmcnt (never 0 in
// steady state), raw s_barrier: ONE barrier per K-step, 2 stages in flight.
// 16B-slot XOR swizzle (pre-swizzled global src + swizzled ds_read).
// Bijective XCD chunk swizzle.
// Epilogue: if xb_epi && zstate[1] (filter == q0*I), fuse the fast-path
// Horner: write relu(q0*v) bf16 into XB slice (+ bern slice with +x).
// Else outB!=0 -> bf16 store, else fp32.
// ---------------------------------------------------------------------------
__global__ __launch_bounds__(256) void mfma_gemm_kernel(
    int Kd,
    const unsigned short* __restrict__ A, int lda,
    const unsigned short* __restrict__ Wt, int ldw,
    const float* __restrict__ bias,
    float* __restrict__ outF, unsigned short* __restrict__ outB, int ldo,
    const float* __restrict__ qf, const int* __restrict__ zstate,
    unsigned short* __restrict__ xb_epi, unsigned short* __restrict__ bern_epi,
    int layer) {
  __shared__ __align__(16) unsigned short Asl[4][128 * 32];
  __shared__ __align__(16) unsigned short Bsl[4][128 * 32];
  const int t    = threadIdx.x;
  const int lane = t & 63;
  const int wid  = t >> 6;
  const int wr   = wid >> 1, wc = wid & 1;

  const int gx  = gridDim.x;
  const int nwg = gx * gridDim.y;
  int bid = blockIdx.y * gx + blockIdx.x;
  if ((nwg & 7) == 0) bid = (bid & 7) * (nwg >> 3) + (bid >> 3);
  const int row0 = (bid / gx) * 128;
  const int col0 = (bid % gx) * 128;

  f32x4 acc[4][4] = {};

  const int swz    = ((lane & 3) ^ ((lane >> 3) & 3)) * 8;
  const int subrow = lane >> 2;
  const int fr = lane & 15;
  const int fq = lane >> 4;

  const int nkt = Kd >> 5;

  auto stage = [&](int kt, int pb) {
    const int kbase = kt << 5;
#pragma unroll
    for (int i = 0; i < 4; ++i) {
      const int c = wid * 4 + i;                 // 0..15; <8 = A, else B
      if (c < 8) {
        const int r = row0 + c * 16 + subrow;
        gload16(A + (size_t)r * lda + kbase + swz, &Asl[pb][c * 512]);
      } else {
        const int cc = c - 8;
        const int r = col0 + cc * 16 + subrow;
        gload16(Wt + (size_t)r * ldw + kbase + swz, &Bsl[pb][cc * 512]);
      }
    }
  };

  stage(0, 0);
  if (nkt > 1) stage(1, 1);

  for (int kt = 0; kt < nkt; ++kt) {
    const int pb = kt & 3;
    if (kt + 2 < nkt) {
      stage(kt + 2, (kt + 2) & 3);
      asm volatile("s_waitcnt vmcnt(8)" ::: "memory");
    } else if (kt + 1 < nkt) {
      asm volatile("s_waitcnt vmcnt(4)" ::: "memory");
    } else {
      asm volatile("s_waitcnt vmcnt(0)" ::: "memory");
    }
    __builtin_amdgcn_s_barrier();
    asm volatile("" ::: "memory");

    short8 af[4], bfr[4];
#pragma unroll
    for (int m = 0; m < 4; ++m) {
      const int r = wr * 64 + m * 16 + fr;
      const int colb = (fq * 16) ^ (((r >> 1) & 3) << 4);
      af[m] = *(const short8*)((const char*)&Asl[pb][0] + r * 64 + colb);
    }
#pragma unroll
    for (int n = 0; n < 4; ++n) {
      const int r = wc * 64 + n * 16 + fr;
      const int colb = (fq * 16) ^ (((r >> 1) & 3) << 4);
      bfr[n] = *(const short8*)((const char*)&Bsl[pb][0] + r * 64 + colb);
    }
    __builtin_amdgcn_s_setprio(1);
#pragma unroll
    for (int m = 0; m < 4; ++m)
#pragma unroll
      for (int n = 0; n < 4; ++n)
        acc[m][n] = __builtin_amdgcn_mfma_f32_16x16x32_bf16(af[m], bfr[n],
                                                            acc[m][n], 0, 0, 0);
    __builtin_amdgcn_s_setprio(0);
  }

  // epilogue: C/D layout col = lane&15, row = (lane>>4)*4 + reg
  int fastepi = 0; float q0 = 0.f;
  if (xb_epi) { fastepi = zstate[1]; q0 = qf[0]; }
#pragma unroll
  for (int n = 0; n < 4; ++n) {
    const int col = col0 + wc * 64 + n * 16 + fr;
    const float bv = bias[col];
#pragma unroll
    for (int m = 0; m < 4; ++m) {
      const int rbase = row0 + wr * 64 + m * 16 + fq * 4;
#pragma unroll
      for (int r = 0; r < 4; ++r) {
        const float v = acc[m][n][r] + bv;
        const size_t rr = (size_t)(rbase + r);
        if (fastepi) {
          const float hv = fmaxf(q0 * v, 0.f);
          const unsigned short hb = f2bf(hv);
          xb_epi[rr * XBW + 768 + layer * HD + col] = hb;
          if (bern_epi)
            bern_epi[rr * 768 + layer * HD + col] =
                f2bf(bf2f(hb) + bf2f(xb_epi[rr * XBW + layer * HD + col]));
        } else if (outB) {
          outB[rr * ldo + col] = f2bf(v);
        } else {
          outF[rr * ldo + col] = v;
        }
      }
    }
  }
}

// ---------------------------------------------------------------------------
// Fused Horner: all K+1 steps for one (graph, 4-channel slab) in one block.
// fused=1 && zstate[1]: GEMM epilogue already did the work -> immediate exit.
// zstate[1] (not fused): relu-copy fast path (+ bern).
// General path: acc ping-pong in LDS, dis/cnt staged, zstate skipping.
// ---------------------------------------------------------------------------
__global__ __launch_bounds__(256, 1) void horner_kernel(
    const unsigned short* __restrict__ h,        // [NROWS][HD] bf16
    const int* __restrict__ cnt, const float* __restrict__ dis,
    const unsigned short* __restrict__ colidx,
    const float* __restrict__ qf, const int* __restrict__ zstate,
    unsigned short* __restrict__ XB, unsigned short* __restrict__ bern,
    int layer, int fused) {
  __shared__ float accA[NB * 4];
  __shared__ float accB[NB * 4];
  __shared__ float dls[NB];
  __shared__ int   cls[NB];
  const int blk = blockIdx.x;                    // 512 = 8 graphs * 64 slabs
  const int b   = blk >> 6;
  const int ch0 = (blk & 63) * 4;
  const int t   = threadIdx.x;
  const size_t rowbase = (size_t)b * NB;

  if (zstate[1]) {
    if (fused) return;                           // epilogue already did it
    const float q0 = qf[0];
    for (int r = t; r < NB; r += 256) {
      union { unsigned short s[4]; uint2 u; } iv, ov, xv, bv;
      iv.u = *(const uint2*)&h[(rowbase + r) * HD + ch0];
#pragma unroll
      for (int j = 0; j < 4; ++j)
        ov.s[j] = f2bf(fmaxf(q0 * bf2f(iv.s[j]), 0.f));
      *(uint2*)&XB[(rowbase + r) * XBW + 768 + layer * HD + ch0] = ov.u;
      if (bern) {
        xv.u = *(const uint2*)&XB[(rowbase + r) * XBW + layer * HD + ch0];
#pragma unroll
        for (int j = 0; j < 4; ++j)
          bv.s[j] = f2bf(bf2f(ov.s[j]) + bf2f(xv.s[j]));
        *(uint2*)&bern[(rowbase + r) * 768 + layer * HD + ch0] = bv.u;
      }
    }
    return;
  }

  for (int r = t; r < NB; r += 256) {
    dls[r] = dis[rowbase + r];
    cls[r] = cnt[rowbase + r];
  }
  __syncthreads();
  float* cur = accA;
  float* nxt = accB;
  const int ch = t & 3;
  for (int m = KORD; m >= 0; --m) {
    if (m == 0 || !zstate[m]) {
      const float qm = qf[m];
      const int gather = !zstate[m + 1];
      for (int r = t >> 2; r < NB; r += 64) {
        float s = 0.f;
        if (gather) {
          const int deg = cls[r];
          const float di = dls[r];
          const unsigned short* ci = colidx + (rowbase + r) * MAXDEG;
          for (int e = 0; e < deg; ++e) {
            const int nb = ci[e];
            s += di * dls[nb] * cur[nb * 4 + ch];
          }
        }
        if (qm != 0.f) s += qm * bf2f(h[(rowbase + r) * HD + ch0 + ch]);
        if (m == 0) {
          const float hv = fmaxf(s, 0.f);
          XB[(rowbase + r) * XBW + 768 + layer * HD + ch0 + ch] = f2bf(hv);
          if (bern)
            bern[(rowbase + r) * 768 + layer * HD + ch0 + ch] = f2bf(
                hv + bf2f(XB[(rowbase + r) * XBW + layer * HD + ch0 + ch]));
        } else {
          nxt[r * 4 + ch] = s;
        }
      }
    }
    __syncthreads();
    float* tp = cur; cur = nxt; nxt = tp;
  }
}

// ---------------------------------------------------------------------------
extern "C" void kernel_launch(void* const* d_in, const int* in_sizes, int n_in,
                              void* d_out, int out_size, void* d_ws, size_t ws_size,
                              hipStream_t stream) {
  const float* adj  = (const float*)d_in[0];
  const float* x    = (const float*)d_in[1];
  const float* coe  = (const float*)d_in[2];
  const float* W0   = (const float*)d_in[3];
  const float* b0   = (const float*)d_in[4];
  const float* W1   = (const float*)d_in[5];
  const float* b1   = (const float*)d_in[6];
  const float* W2   = (const float*)d_in[7];
  const float* b2   = (const float*)d_in[8];
  const float* Wout = (const float*)d_in[9];
  const float* bout = (const float*)d_in[10];
  float* outp = (float*)d_out;

  // bufH (GEMM output when the general Horner path is live, bf16) lives in
  // d_out; dead by the time the final GEMM overwrites d_out.
  unsigned short* bufH = (unsigned short*)outp;

  char* ws = (char*)d_ws;
  size_t off = 0;
  float* qf     = (float*)(ws + off); off += 256;
  int*   zstate = (int*)(ws + off);   off += 256;
  int*   cnt    = (int*)(ws + off);   off += 65536;
  float* dis    = (float*)(ws + off); off += 65536;
  unsigned short* colidx = (unsigned short*)(ws + off); off += (size_t)NROWS * MAXDEG * 2;
  unsigned short* XB     = (unsigned short*)(ws + off); off += (size_t)NROWS * XBW * 2;
  unsigned short* Wt0 = (unsigned short*)(ws + off); off += (size_t)256 * 768 * 2;
  unsigned short* Wt1 = (unsigned short*)(ws + off); off += (size_t)256 * 1024 * 2;
  unsigned short* Wt2 = (unsigned short*)(ws + off); off += (size_t)256 * 1280 * 2;
  unsigned short* WtO = (unsigned short*)(ws + off); off += (size_t)768 * 1536 * 2;
  unsigned short* bern = (unsigned short*)(ws + off);
  const size_t need = off + (size_t)NROWS * 768 * 2;   // ~77.9 MB
  const int split = ws_size >= need;                   // bern fits in ws?
  unsigned short* bernp = split ? bern : (unsigned short*)nullptr;

  hipLaunchKernelGGL(prep_kernel, dim3(8065), dim3(256), 0, stream,
                     adj, x, coe, W0, W1, W2, Wout,
                     cnt, dis, colidx, XB, Wt0, Wt1, Wt2, WtO, qf, zstate);

  // layer l: h = [x|h0|..] @ Wl + bl (bf16 MFMA, fast-Horner fused in
  // epilogue when zstate[1]); then Horner (early-exits if fused).
  auto layer = [&](int Kd, const unsigned short* Wt, const float* bias, int l) {
    hipLaunchKernelGGL(mfma_gemm_kernel, dim3(2, 128), dim3(256), 0, stream,
                       Kd, XB, XBW, Wt, Kd, bias, (float*)nullptr, bufH, HD,
                       qf, zstate, XB, bernp, l);
    hipLaunchKernelGGL(horner_kernel, dim3(512), dim3(256), 0, stream,
                       bufH, cnt, dis, colidx, qf, zstate, XB, bernp, l, 1);
  };
  layer(768,  Wt0, b0, 0);
  layer(1024, Wt1, b1, 1);
  layer(1280, Wt2, b2, 2);

  // out = bern @ Wout + bout (split: K=768 on materialized bern)
  //     = [x | h0h1h2] @ [Wout ; Wout] + bout (fallback: K=1536 dup)
  if (split)
    hipLaunchKernelGGL(mfma_gemm_kernel, dim3(6, 128), dim3(256), 0, stream,
                       768, bern, 768, WtO, 1536, bout, outp,
                       (unsigned short*)nullptr, 768,
                       qf, zstate, (unsigned short*)nullptr,
                       (unsigned short*)nullptr, 0);
  else
    hipLaunchKernelGGL(mfma_gemm_kernel, dim3(6, 128), dim3(256), 0, stream,
                       1536, XB, XBW, WtO, 1536, bout, outp,
                       (unsigned short*)nullptr, 768,
                       qf, zstate, (unsigned short*)nullptr,
                       (unsigned short*)nullptr, 0);
}

// Round 6
// 178.092 us; speedup vs baseline: 5.4319x; 1.3780x over previous
//
#include <hip/hip_runtime.h>

#define KORD   10
#define MAXDEG 64
#define NB     2048        // nodes per graph
#define NROWS  16384       // 8 * 2048
#define HD     256         // hidden per conv
#define XBW    1536        // XB width: [x(768) | h0(256) | h1(256) | h2(256)]

typedef __attribute__((ext_vector_type(8))) short short8;
typedef __attribute__((ext_vector_type(4))) float f32x4;

__device__ inline unsigned short f2bf(float f) {
  union { float f; unsigned u; } v; v.f = f;
  unsigned r = v.u + 0x7fff + ((v.u >> 16) & 1);   // round-to-nearest-even
  return (unsigned short)(r >> 16);
}
__device__ inline float bf2f(unsigned short b) {
  union { unsigned u; float f; } v; v.u = ((unsigned)b) << 16;
  return v.f;
}

#define AS1 __attribute__((address_space(1)))
#define AS3 __attribute__((address_space(3)))
__device__ inline void gload16(const void* g, void* l) {
  // 16B per lane, global (per-lane addr) -> LDS (wave-uniform base + lane*16)
  __builtin_amdgcn_global_load_lds((const AS1 void*)g, (AS3 void*)l, 16, 0, 0);
}

// ---------------------------------------------------------------------------
// Exact integer binomial in fp64 (all intermediates are exact ints < 2^53).
// ---------------------------------------------------------------------------
__device__ inline double binom_d(int n, int r) {
  if (r < 0 || r > n) return 0.0;
  double v = 1.0;
  for (int i = 1; i <= r; ++i) v = v * (double)(n - r + i) / (double)i;
  return v;
}

// ---------------------------------------------------------------------------
// q[m] = [z^m] sum_k relu(coe[k]) * C(K,k)/2^K * (1-z)^k (1+z)^{K-k}
// zstate[m] = 1 iff q[j]==0 for all j>=m. Exact in fp64 for dyadic coe
// (e.g. coe=1 -> q = [1,0,...,0] exactly). 121 threads: one per (k,m).
// ---------------------------------------------------------------------------
__global__ __launch_bounds__(128) void qz_kernel(const float* __restrict__ coe,
                                                 float* __restrict__ qf,
                                                 int* __restrict__ zstate) {
  __shared__ double part[(KORD + 1) * (KORD + 1)];   // [k][m]
  __shared__ double qs[KORD + 1];
  const int t = threadIdx.x;
  if (t < (KORD + 1) * (KORD + 1)) {
    const int k = t / (KORD + 1), m = t % (KORD + 1);
    double tt = (double)coe[k];
    if (tt < 0.0) tt = 0.0;                          // relu(coe)
    const double ck = tt * binom_d(KORD, k) / 1024.0;
    double s = 0.0;
    for (int j = 0; j <= k && j <= m; ++j) {
      const int rem = m - j;
      if (rem <= KORD - k) {
        const double term = binom_d(k, j) * binom_d(KORD - k, rem);
        s += (j & 1) ? -term : term;
      }
    }
    part[t] = ck * s;
  }
  __syncthreads();
  if (t <= KORD) {
    double q = 0.0;
    for (int k = 0; k <= KORD; ++k) q += part[k * (KORD + 1) + t];
    qs[t] = q;
    qf[t] = (float)q;
  }
  __syncthreads();
  if (t == 0) {
    zstate[KORD + 1] = 1;
    int z = 1;
    for (int m = KORD; m >= 0; --m) {
      if (qs[m] != 0.0) z = 0;
      zstate[m] = z;
    }
  }
}

// ---------------------------------------------------------------------------
// Fused prep: one dispatch, branch by block range.
//   [0,4096)      build_adj: adjacency lists + deg + D^-1/2 (wave per row).
//                 RUNTIME-DEAD when zstate[1] (filter == q0*I): no consumer
//                 reads colidx/cnt/dis then -> early-exit the whole section.
//   [4096,6144)   xcvt: x fp32 -> XB bf16 cols [0,768)
//   [6144,8064)   wcvt x5: W [K][N] fp32 -> Wt [N][ldt] bf16 transposed
// ---------------------------------------------------------------------------
__global__ __launch_bounds__(256) void prep_kernel(
    const float* __restrict__ adj, const float* __restrict__ x,
    const float* __restrict__ W0, const float* __restrict__ W1,
    const float* __restrict__ W2, const float* __restrict__ Wout,
    const int* __restrict__ zstate,
    int* __restrict__ cnt, float* __restrict__ dis,
    unsigned short* __restrict__ colidx,
    unsigned short* __restrict__ XB,
    unsigned short* __restrict__ Wt0, unsigned short* __restrict__ Wt1,
    unsigned short* __restrict__ Wt2, unsigned short* __restrict__ WtO) {
  __shared__ float tile[32][33];
  const int blk = blockIdx.x;
  const int t = threadIdx.x;

  if (blk < 4096) {                       // ---- build_adj ----
    if (zstate[1]) return;                // outputs never consumed: skip
    const int wave = t >> 6;
    const int lane = t & 63;
    const int row  = blk * 4 + wave;
    const float4* arow4 = (const float4*)(adj + (size_t)row * NB);
    unsigned short* ci = colidx + (size_t)row * MAXDEG;
    float4 v[8];
#pragma unroll
    for (int i = 0; i < 8; ++i) v[i] = arow4[i * 64 + lane];
    const unsigned long long lower = (1ull << lane) - 1ull;
    int base = 0;
#pragma unroll
    for (int i = 0; i < 8; ++i) {
      const int col = i * 256 + lane * 4;
      const int b0 = v[i].x > 0.f, b1 = v[i].y > 0.f;
      const int b2 = v[i].z > 0.f, b3 = v[i].w > 0.f;
      const unsigned long long m0 = __ballot(b0), m1 = __ballot(b1);
      const unsigned long long m2 = __ballot(b2), m3 = __ballot(b3);
      int pre = base + __popcll(m0 & lower) + __popcll(m1 & lower) +
                __popcll(m2 & lower) + __popcll(m3 & lower);
      if (b0) { if (pre < MAXDEG) ci[pre] = (unsigned short)col; ++pre; }
      if (b1) { if (pre < MAXDEG) ci[pre] = (unsigned short)(col + 1); ++pre; }
      if (b2) { if (pre < MAXDEG) ci[pre] = (unsigned short)(col + 2); ++pre; }
      if (b3) { if (pre < MAXDEG) ci[pre] = (unsigned short)(col + 3); ++pre; }
      base += __popcll(m0) + __popcll(m1) + __popcll(m2) + __popcll(m3);
    }
    if (lane == 0) {
      cnt[row] = base > MAXDEG ? MAXDEG : base;
      dis[row] = base > 0 ? rsqrtf((float)base) : 0.0f;
    }
    return;
  }

  if (blk < 6144) {                       // ---- xcvt: 8 rows per block ----
    const int r0 = (blk - 4096) * 8;
    for (int i = t; i < 8 * 192; i += 256) {
      const int r = r0 + (i / 192);
      const int c = (i % 192) * 4;
      float4 v = *(const float4*)&x[(size_t)r * 768 + c];
      union { unsigned short s[4]; uint2 u; } o;
      o.s[0] = f2bf(v.x); o.s[1] = f2bf(v.y);
      o.s[2] = f2bf(v.z); o.s[3] = f2bf(v.w);
      *(uint2*)&XB[(size_t)r * XBW + c] = o.u;
    }
    return;
  }

  // ---- wcvt (5 jobs) ----
  const float* W; unsigned short* Wt; int N, ldt, koff, gx, lb;
  int b = blk - 6144;
  if (b < 192)       { W = W0;   Wt = Wt0; N = 256; ldt = 768;  koff = 0;   gx = 24; lb = b; }
  else if (b < 448)  { W = W1;   Wt = Wt1; N = 256; ldt = 1024; koff = 0;   gx = 32; lb = b - 192; }
  else if (b < 768)  { W = W2;   Wt = Wt2; N = 256; ldt = 1280; koff = 0;   gx = 40; lb = b - 448; }
  else if (b < 1344) { W = Wout; Wt = WtO; N = 768; ldt = 1536; koff = 0;   gx = 24; lb = b - 768; }
  else               { W = Wout; Wt = WtO; N = 768; ldt = 1536; koff = 768; gx = 24; lb = b - 1344; }
  const int k0 = (lb % gx) * 32, n0 = (lb / gx) * 32;
  const int tx = t & 31, ty = t >> 5;
#pragma unroll
  for (int i = 0; i < 4; ++i)
    tile[ty + 8 * i][tx] = W[(size_t)(k0 + ty + 8 * i) * N + n0 + tx];
  __syncthreads();
#pragma unroll
  for (int i = 0; i < 4; ++i)
    Wt[(size_t)(n0 + ty + 8 * i) * ldt + koff + k0 + tx] =
        f2bf(tile[tx][ty + 8 * i]);
}

// ---------------------------------------------------------------------------
// bf16 MFMA GEMM: out[M=16384, N] = A[M,Kd] @ Wt[N,Kd]^T + bias
// BM=BN=128, BK=32, 4 waves. 4-buffer LDS ring, counted vmcnt (never 0 in
// steady state), raw s_barrier: ONE barrier per K-step, 2 stages in flight.
// 16B-slot XOR swizzle (pre-swizzled global src + swizzled ds_read).
// Bijective XCD chunk swizzle.
// Epilogue: if xb_epi && zstate[1] (filter == q0*I), fuse the fast-path
// Horner: write relu(q0*v) bf16 into XB slice (+ bern slice with +x).
// Else outB!=0 -> bf16 store, else fp32.
// ---------------------------------------------------------------------------
__global__ __launch_bounds__(256) void mfma_gemm_kernel(
    int Kd,
    const unsigned short* __restrict__ A, int lda,
    const unsigned short* __restrict__ Wt, int ldw,
    const float* __restrict__ bias,
    float* __restrict__ outF, unsigned short* __restrict__ outB, int ldo,
    const float* __restrict__ qf, const int* __restrict__ zstate,
    unsigned short* __restrict__ xb_epi, unsigned short* __restrict__ bern_epi,
    int layer) {
  __shared__ __align__(16) unsigned short Asl[4][128 * 32];
  __shared__ __align__(16) unsigned short Bsl[4][128 * 32];
  const int t    = threadIdx.x;
  const int lane = t & 63;
  const int wid  = t >> 6;
  const int wr   = wid >> 1, wc = wid & 1;

  const int gx  = gridDim.x;
  const int nwg = gx * gridDim.y;
  int bid = blockIdx.y * gx + blockIdx.x;
  if ((nwg & 7) == 0) bid = (bid & 7) * (nwg >> 3) + (bid >> 3);
  const int row0 = (bid / gx) * 128;
  const int col0 = (bid % gx) * 128;

  f32x4 acc[4][4] = {};

  const int swz    = ((lane & 3) ^ ((lane >> 3) & 3)) * 8;
  const int subrow = lane >> 2;
  const int fr = lane & 15;
  const int fq = lane >> 4;

  const int nkt = Kd >> 5;

  auto stage = [&](int kt, int pb) {
    const int kbase = kt << 5;
#pragma unroll
    for (int i = 0; i < 4; ++i) {
      const int c = wid * 4 + i;                 // 0..15; <8 = A, else B
      if (c < 8) {
        const int r = row0 + c * 16 + subrow;
        gload16(A + (size_t)r * lda + kbase + swz, &Asl[pb][c * 512]);
      } else {
        const int cc = c - 8;
        const int r = col0 + cc * 16 + subrow;
        gload16(Wt + (size_t)r * ldw + kbase + swz, &Bsl[pb][cc * 512]);
      }
    }
  };

  stage(0, 0);
  if (nkt > 1) stage(1, 1);

  for (int kt = 0; kt < nkt; ++kt) {
    const int pb = kt & 3;
    if (kt + 2 < nkt) {
      stage(kt + 2, (kt + 2) & 3);
      asm volatile("s_waitcnt vmcnt(8)" ::: "memory");
    } else if (kt + 1 < nkt) {
      asm volatile("s_waitcnt vmcnt(4)" ::: "memory");
    } else {
      asm volatile("s_waitcnt vmcnt(0)" ::: "memory");
    }
    __builtin_amdgcn_s_barrier();
    asm volatile("" ::: "memory");

    short8 af[4], bfr[4];
#pragma unroll
    for (int m = 0; m < 4; ++m) {
      const int r = wr * 64 + m * 16 + fr;
      const int colb = (fq * 16) ^ (((r >> 1) & 3) << 4);
      af[m] = *(const short8*)((const char*)&Asl[pb][0] + r * 64 + colb);
    }
#pragma unroll
    for (int n = 0; n < 4; ++n) {
      const int r = wc * 64 + n * 16 + fr;
      const int colb = (fq * 16) ^ (((r >> 1) & 3) << 4);
      bfr[n] = *(const short8*)((const char*)&Bsl[pb][0] + r * 64 + colb);
    }
    __builtin_amdgcn_s_setprio(1);
#pragma unroll
    for (int m = 0; m < 4; ++m)
#pragma unroll
      for (int n = 0; n < 4; ++n)
        acc[m][n] = __builtin_amdgcn_mfma_f32_16x16x32_bf16(af[m], bfr[n],
                                                            acc[m][n], 0, 0, 0);
    __builtin_amdgcn_s_setprio(0);
  }

  // epilogue: C/D layout col = lane&15, row = (lane>>4)*4 + reg
  int fastepi = 0; float q0 = 0.f;
  if (xb_epi) { fastepi = zstate[1]; q0 = qf[0]; }
#pragma unroll
  for (int n = 0; n < 4; ++n) {
    const int col = col0 + wc * 64 + n * 16 + fr;
    const float bv = bias[col];
#pragma unroll
    for (int m = 0; m < 4; ++m) {
      const int rbase = row0 + wr * 64 + m * 16 + fq * 4;
#pragma unroll
      for (int r = 0; r < 4; ++r) {
        const float v = acc[m][n][r] + bv;
        const size_t rr = (size_t)(rbase + r);
        if (fastepi) {
          const float hv = fmaxf(q0 * v, 0.f);
          const unsigned short hb = f2bf(hv);
          xb_epi[rr * XBW + 768 + layer * HD + col] = hb;
          if (bern_epi)
            bern_epi[rr * 768 + layer * HD + col] =
                f2bf(bf2f(hb) + bf2f(xb_epi[rr * XBW + layer * HD + col]));
        } else if (outB) {
          outB[rr * ldo + col] = f2bf(v);
        } else {
          outF[rr * ldo + col] = v;
        }
      }
    }
  }
}

// ---------------------------------------------------------------------------
// Fused Horner: all K+1 steps for one (graph, 4-channel slab) in one block.
// fused=1 && zstate[1]: GEMM epilogue already did the work -> immediate exit.
// zstate[1] (not fused): relu-copy fast path (+ bern).
// General path: acc ping-pong in LDS, dis/cnt staged, zstate skipping.
// ---------------------------------------------------------------------------
__global__ __launch_bounds__(256, 1) void horner_kernel(
    const unsigned short* __restrict__ h,        // [NROWS][HD] bf16
    const int* __restrict__ cnt, const float* __restrict__ dis,
    const unsigned short* __restrict__ colidx,
    const float* __restrict__ qf, const int* __restrict__ zstate,
    unsigned short* __restrict__ XB, unsigned short* __restrict__ bern,
    int layer, int fused) {
  __shared__ float accA[NB * 4];
  __shared__ float accB[NB * 4];
  __shared__ float dls[NB];
  __shared__ int   cls[NB];
  const int blk = blockIdx.x;                    // 512 = 8 graphs * 64 slabs
  const int b   = blk >> 6;
  const int ch0 = (blk & 63) * 4;
  const int t   = threadIdx.x;
  const size_t rowbase = (size_t)b * NB;

  if (zstate[1]) {
    if (fused) return;                           // epilogue already did it
    const float q0 = qf[0];
    for (int r = t; r < NB; r += 256) {
      union { unsigned short s[4]; uint2 u; } iv, ov, xv, bv;
      iv.u = *(const uint2*)&h[(rowbase + r) * HD + ch0];
#pragma unroll
      for (int j = 0; j < 4; ++j)
        ov.s[j] = f2bf(fmaxf(q0 * bf2f(iv.s[j]), 0.f));
      *(uint2*)&XB[(rowbase + r) * XBW + 768 + layer * HD + ch0] = ov.u;
      if (bern) {
        xv.u = *(const uint2*)&XB[(rowbase + r) * XBW + layer * HD + ch0];
#pragma unroll
        for (int j = 0; j < 4; ++j)
          bv.s[j] = f2bf(bf2f(ov.s[j]) + bf2f(xv.s[j]));
        *(uint2*)&bern[(rowbase + r) * 768 + layer * HD + ch0] = bv.u;
      }
    }
    return;
  }

  for (int r = t; r < NB; r += 256) {
    dls[r] = dis[rowbase + r];
    cls[r] = cnt[rowbase + r];
  }
  __syncthreads();
  float* cur = accA;
  float* nxt = accB;
  const int ch = t & 3;
  for (int m = KORD; m >= 0; --m) {
    if (m == 0 || !zstate[m]) {
      const float qm = qf[m];
      const int gather = !zstate[m + 1];
      for (int r = t >> 2; r < NB; r += 64) {
        float s = 0.f;
        if (gather) {
          const int deg = cls[r];
          const float di = dls[r];
          const unsigned short* ci = colidx + (rowbase + r) * MAXDEG;
          for (int e = 0; e < deg; ++e) {
            const int nb = ci[e];
            s += di * dls[nb] * cur[nb * 4 + ch];
          }
        }
        if (qm != 0.f) s += qm * bf2f(h[(rowbase + r) * HD + ch0 + ch]);
        if (m == 0) {
          const float hv = fmaxf(s, 0.f);
          XB[(rowbase + r) * XBW + 768 + layer * HD + ch0 + ch] = f2bf(hv);
          if (bern)
            bern[(rowbase + r) * 768 + layer * HD + ch0 + ch] = f2bf(
                hv + bf2f(XB[(rowbase + r) * XBW + layer * HD + ch0 + ch]));
        } else {
          nxt[r * 4 + ch] = s;
        }
      }
    }
    __syncthreads();
    float* tp = cur; cur = nxt; nxt = tp;
  }
}

// ---------------------------------------------------------------------------
extern "C" void kernel_launch(void* const* d_in, const int* in_sizes, int n_in,
                              void* d_out, int out_size, void* d_ws, size_t ws_size,
                              hipStream_t stream) {
  const float* adj  = (const float*)d_in[0];
  const float* x    = (const float*)d_in[1];
  const float* coe  = (const float*)d_in[2];
  const float* W0   = (const float*)d_in[3];
  const float* b0   = (const float*)d_in[4];
  const float* W1   = (const float*)d_in[5];
  const float* b1   = (const float*)d_in[6];
  const float* W2   = (const float*)d_in[7];
  const float* b2   = (const float*)d_in[8];
  const float* Wout = (const float*)d_in[9];
  const float* bout = (const float*)d_in[10];
  float* outp = (float*)d_out;

  // bufH (GEMM output when the general Horner path is live, bf16) lives in
  // d_out; dead by the time the final GEMM overwrites d_out.
  unsigned short* bufH = (unsigned short*)outp;

  char* ws = (char*)d_ws;
  size_t off = 0;
  float* qf     = (float*)(ws + off); off += 256;
  int*   zstate = (int*)(ws + off);   off += 256;
  int*   cnt    = (int*)(ws + off);   off += 65536;
  float* dis    = (float*)(ws + off); off += 65536;
  unsigned short* colidx = (unsigned short*)(ws + off); off += (size_t)NROWS * MAXDEG * 2;
  unsigned short* XB     = (unsigned short*)(ws + off); off += (size_t)NROWS * XBW * 2;
  unsigned short* Wt0 = (unsigned short*)(ws + off); off += (size_t)256 * 768 * 2;
  unsigned short* Wt1 = (unsigned short*)(ws + off); off += (size_t)256 * 1024 * 2;
  unsigned short* Wt2 = (unsigned short*)(ws + off); off += (size_t)256 * 1280 * 2;
  unsigned short* WtO = (unsigned short*)(ws + off); off += (size_t)768 * 1536 * 2;
  unsigned short* bern = (unsigned short*)(ws + off);
  const size_t need = off + (size_t)NROWS * 768 * 2;   // ~77.9 MB
  const int split = ws_size >= need;                   // bern fits in ws?
  unsigned short* bernp = split ? bern : (unsigned short*)nullptr;

  hipLaunchKernelGGL(qz_kernel, dim3(1), dim3(128), 0, stream, coe, qf, zstate);
  hipLaunchKernelGGL(prep_kernel, dim3(8064), dim3(256), 0, stream,
                     adj, x, W0, W1, W2, Wout, zstate,
                     cnt, dis, colidx, XB, Wt0, Wt1, Wt2, WtO);

  // layer l: h = [x|h0|..] @ Wl + bl (bf16 MFMA, fast-Horner fused in
  // epilogue when zstate[1]); then Horner (early-exits if fused).
  auto layer = [&](int Kd, const unsigned short* Wt, const float* bias, int l) {
    hipLaunchKernelGGL(mfma_gemm_kernel, dim3(2, 128), dim3(256), 0, stream,
                       Kd, XB, XBW, Wt, Kd, bias, (float*)nullptr, bufH, HD,
                       qf, zstate, XB, bernp, l);
    hipLaunchKernelGGL(horner_kernel, dim3(512), dim3(256), 0, stream,
                       bufH, cnt, dis, colidx, qf, zstate, XB, bernp, l, 1);
  };
  layer(768,  Wt0, b0, 0);
  layer(1024, Wt1, b1, 1);
  layer(1280, Wt2, b2, 2);

  // out = bern @ Wout + bout (split: K=768 on materialized bern)
  //     = [x | h0h1h2] @ [Wout ; Wout] + bout (fallback: K=1536 dup)
  if (split)
    hipLaunchKernelGGL(mfma_gemm_kernel, dim3(6, 128), dim3(256), 0, stream,
                       768, bern, 768, WtO, 1536, bout, outp,
                       (unsigned short*)nullptr, 768,
                       qf, zstate, (unsigned short*)nullptr,
                       (unsigned short*)nullptr, 0);
  else
    hipLaunchKernelGGL(mfma_gemm_kernel, dim3(6, 128), dim3(256), 0, stream,
                       1536, XB, XBW, WtO, 1536, bout, outp,
                       (unsigned short*)nullptr, 768,
                       qf, zstate, (unsigned short*)nullptr,
                       (unsigned short*)nullptr, 0);
}